// Round 6
// baseline (2064.184 us; speedup 1.0000x reference)
//
#include <hip/hip_runtime.h>
#include <hip/hip_bf16.h>
#include <cfloat>
#include <math.h>

// Problem constants
#define BB 8
#define NN 256
#define BN 2048           // B*N
#define DD 128            // descriptor dim
#define FEAT 130          // 2 + 128

// ---------------------------------------------------------------------------
// Kernel 1: point prep (unchanged)
// ---------------------------------------------------------------------------
__global__ __launch_bounds__(256) void prep_kernel(
    const float* __restrict__ theta,
    const float* __restrict__ feat1,   // my_feature   (BN,130)
    const float* __restrict__ feat2,   // my_tf_feature(BN,130)
    const int* __restrict__ wp, const int* __restrict__ hp,
    float* __restrict__ pts1, float* __restrict__ pts2) {
  int i = blockIdx.x * 256 + threadIdx.x;
  if (i >= BN) return;
  double W = (double)wp[0], H = (double)hp[0];
  double th = (double)theta[0];
  double c = cos(th), s = sin(th);
  double kx = (double)feat1[(size_t)i * FEAT + 0];
  double ky = (double)feat1[(size_t)i * FEAT + 1];
  double x = kx - 0.5 * W;
  double y = -ky + 0.5 * H;
  double calx = rint(c * x - s * y);   // jnp.round == round-half-even == rint
  double caly = rint(s * x + c * y);
  double ox = calx + 0.5 * W;
  double oy = -caly + 0.5 * H;
  pts2[2 * i]     = (float)(int)ox;    // astype(int32): trunc toward zero
  pts2[2 * i + 1] = (float)(int)oy;
  pts1[2 * i]     = (float)(int)feat2[(size_t)i * FEAT + 0];
  pts1[2 * i + 1] = (float)(int)feat2[(size_t)i * FEAT + 1];
}

// ---------------------------------------------------------------------------
// Kernel 2: fundamental 8-point (f64), unchanged from R5 (passing).
// ---------------------------------------------------------------------------
__device__ inline double wred(double x) {
#pragma unroll
  for (int off = 32; off > 0; off >>= 1) x += __shfl_down(x, off, 64);
  return x;
}

#define JROT(P, Q) {                                                          \
  double app_ = __shfl(Bc[P], P);                                             \
  double aqq_ = __shfl(Bc[Q], Q);                                             \
  double apq_ = __shfl(Bc[P], Q);                                             \
  double c_, s_;                                                              \
  if (fabs(apq_) > 1e-300) {                                                  \
    double tau_ = (aqq_ - app_) / (2.0 * apq_);                               \
    double t_ = (tau_ >= 0.0 ? 1.0 : -1.0) / (fabs(tau_) + sqrt(1.0 + tau_ * tau_)); \
    c_ = 1.0 / sqrt(1.0 + t_ * t_);                                           \
    s_ = t_ * c_;                                                             \
  } else { c_ = 1.0; s_ = 0.0; }                                              \
  const int prt_ = (jln == P) ? Q : ((jln == Q) ? P : jln);                   \
  const bool isP_ = (jln == P), isQ_ = (jln == Q);                            \
  _Pragma("unroll")                                                           \
  for (int ii = 0; ii < 9; ++ii) {                                            \
    double ob_ = __shfl(Bc[ii], prt_);                                        \
    double ov_ = __shfl(Vc[ii], prt_);                                        \
    if (isP_) { Bc[ii] = c_ * Bc[ii] - s_ * ob_; Vc[ii] = c_ * Vc[ii] - s_ * ov_; } \
    if (isQ_) { Bc[ii] = s_ * ob_ + c_ * Bc[ii]; Vc[ii] = s_ * ov_ + c_ * Vc[ii]; } \
  }                                                                           \
  { double rp_ = Bc[P], rq_ = Bc[Q];                                          \
    Bc[P] = c_ * rp_ - s_ * rq_; Bc[Q] = s_ * rp_ + c_ * rq_; } }

#define ROT3(P, Q) {                                                          \
  double apq_ = A3[P][Q];                                                     \
  double c_, s_;                                                              \
  if (fabs(apq_) > 1e-300) {                                                  \
    double tau_ = (A3[Q][Q] - A3[P][P]) / (2.0 * apq_);                       \
    double t_ = (tau_ >= 0.0 ? 1.0 : -1.0) / (fabs(tau_) + sqrt(1.0 + tau_ * tau_)); \
    c_ = 1.0 / sqrt(1.0 + t_ * t_); s_ = t_ * c_;                             \
  } else { c_ = 1.0; s_ = 0.0; }                                              \
  _Pragma("unroll")                                                           \
  for (int ii = 0; ii < 3; ++ii) { double a_ = A3[ii][P], b_ = A3[ii][Q];     \
    A3[ii][P] = c_ * a_ - s_ * b_; A3[ii][Q] = s_ * a_ + c_ * b_; }           \
  _Pragma("unroll")                                                           \
  for (int ii = 0; ii < 3; ++ii) { double a_ = A3[P][ii], b_ = A3[Q][ii];     \
    A3[P][ii] = c_ * a_ - s_ * b_; A3[Q][ii] = s_ * a_ + c_ * b_; }           \
  _Pragma("unroll")                                                           \
  for (int ii = 0; ii < 3; ++ii) { double a_ = V3[ii][P], b_ = V3[ii][Q];     \
    V3[ii][P] = c_ * a_ - s_ * b_; V3[ii][Q] = s_ * a_ + c_ * b_; } }

__global__ __launch_bounds__(256) void fmat_kernel(
    const float* __restrict__ pts1f, const float* __restrict__ pts2f,
    double* __restrict__ Fout) {
  __shared__ double sred[6];
  __shared__ double sATA[45];
  __shared__ double sV[9][16];
  __shared__ double sEv[16];
  const int tid = threadIdx.x;
  const int lane = tid & 63;
  if (tid < 6) sred[tid] = 0.0;
  if (tid < 45) sATA[tid] = 0.0;
  __syncthreads();

  double sx1 = 0, sy1 = 0, sx2 = 0, sy2 = 0;
  for (int p = tid; p < BN; p += 256) {
    sx1 += (double)pts1f[2 * p];     sy1 += (double)pts1f[2 * p + 1];
    sx2 += (double)pts2f[2 * p];     sy2 += (double)pts2f[2 * p + 1];
  }
  sx1 = wred(sx1); sy1 = wred(sy1); sx2 = wred(sx2); sy2 = wred(sy2);
  if (lane == 0) {
    atomicAdd(&sred[0], sx1); atomicAdd(&sred[1], sy1);
    atomicAdd(&sred[2], sx2); atomicAdd(&sred[3], sy2);
  }
  __syncthreads();
  const double m1x = sred[0] * (1.0 / BN), m1y = sred[1] * (1.0 / BN);
  const double m2x = sred[2] * (1.0 / BN), m2y = sred[3] * (1.0 / BN);

  double d1 = 0, d2 = 0;
  for (int p = tid; p < BN; p += 256) {
    double ax = (double)pts1f[2 * p] - m1x, ay = (double)pts1f[2 * p + 1] - m1y;
    double bx = (double)pts2f[2 * p] - m2x, by = (double)pts2f[2 * p + 1] - m2y;
    d1 += sqrt(ax * ax + ay * ay);
    d2 += sqrt(bx * bx + by * by);
  }
  d1 = wred(d1); d2 = wred(d2);
  if (lane == 0) { atomicAdd(&sred[4], d1); atomicAdd(&sred[5], d2); }
  __syncthreads();
  const double s1 = sqrt(2.0) / (sred[4] * (1.0 / BN));
  const double s2 = sqrt(2.0) / (sred[5] * (1.0 / BN));

  double acc45[45];
#pragma unroll
  for (int e = 0; e < 45; ++e) acc45[e] = 0.0;
  for (int p = tid; p < BN; p += 256) {
    double u1 = ((double)pts1f[2 * p]     - m1x) * s1;
    double v1 = ((double)pts1f[2 * p + 1] - m1y) * s1;
    double u2 = ((double)pts2f[2 * p]     - m2x) * s2;
    double v2 = ((double)pts2f[2 * p + 1] - m2y) * s2;
    double r[9] = {u2 * u1, u2 * v1, u2, v2 * u1, v2 * v1, v2, u1, v1, 1.0};
#pragma unroll
    for (int a = 0; a < 9; ++a)
#pragma unroll
      for (int b = a; b < 9; ++b)
        acc45[9 * a - (a * (a - 1)) / 2 + (b - a)] += r[a] * r[b];
  }
#pragma unroll
  for (int e = 0; e < 45; ++e) {
    double vv = wred(acc45[e]);
    if (lane == 0) atomicAdd(&sATA[e], vv);
  }
  __syncthreads();

  if (tid < 64) {
    const int jln = tid;
    double Bc[9], Vc[9];
#pragma unroll
    for (int i2 = 0; i2 < 9; ++i2) {
      if (jln < 9) {
        int a = i2 < jln ? i2 : jln;
        int b = i2 < jln ? jln : i2;
        Bc[i2] = sATA[9 * a - (a * (a - 1)) / 2 + (b - a)];
      } else Bc[i2] = 0.0;
      Vc[i2] = (i2 == jln) ? 1.0 : 0.0;
    }
    for (int sw = 0; sw < 7; ++sw) {
      JROT(0,1) JROT(0,2) JROT(0,3) JROT(0,4) JROT(0,5) JROT(0,6) JROT(0,7) JROT(0,8)
      JROT(1,2) JROT(1,3) JROT(1,4) JROT(1,5) JROT(1,6) JROT(1,7) JROT(1,8)
      JROT(2,3) JROT(2,4) JROT(2,5) JROT(2,6) JROT(2,7) JROT(2,8)
      JROT(3,4) JROT(3,5) JROT(3,6) JROT(3,7) JROT(3,8)
      JROT(4,5) JROT(4,6) JROT(4,7) JROT(4,8)
      JROT(5,6) JROT(5,7) JROT(5,8)
      JROT(6,7) JROT(6,8)
      JROT(7,8)
    }
    double ev = 0.0;
#pragma unroll
    for (int i2 = 0; i2 < 9; ++i2) if (jln == i2) ev = Bc[i2];
    if (jln < 9) {
      sEv[jln] = ev;
#pragma unroll
      for (int i2 = 0; i2 < 9; ++i2) sV[i2][jln] = Vc[i2];
    }
  }
  __syncthreads();

  if (tid == 0) {
    int jm = 0; double be = sEv[0];
#pragma unroll
    for (int jj = 1; jj < 9; ++jj) if (sEv[jj] < be) { be = sEv[jj]; jm = jj; }
    double F0[9];
#pragma unroll
    for (int i2 = 0; i2 < 9; ++i2) F0[i2] = sV[i2][jm];
    double M00 = F0[0], M01 = F0[1], M02 = F0[2];
    double M10 = F0[3], M11 = F0[4], M12 = F0[5];
    double M20 = F0[6], M21 = F0[7], M22 = F0[8];
    double A3[3][3], V3[3][3];
    A3[0][0] = M00*M00 + M10*M10 + M20*M20;
    A3[0][1] = M00*M01 + M10*M11 + M20*M21;
    A3[0][2] = M00*M02 + M10*M12 + M20*M22;
    A3[1][1] = M01*M01 + M11*M11 + M21*M21;
    A3[1][2] = M01*M02 + M11*M12 + M21*M22;
    A3[2][2] = M02*M02 + M12*M12 + M22*M22;
    A3[1][0] = A3[0][1]; A3[2][0] = A3[0][2]; A3[2][1] = A3[1][2];
#pragma unroll
    for (int ii = 0; ii < 3; ++ii)
#pragma unroll
      for (int jj = 0; jj < 3; ++jj) V3[ii][jj] = (ii == jj) ? 1.0 : 0.0;
    for (int sw = 0; sw < 10; ++sw) { ROT3(0,1) ROT3(0,2) ROT3(1,2) }
    double w0 = A3[0][0], w1 = A3[1][1], w2 = A3[2][2];
    double vx, vy, vz;
    if (w0 <= w1 && w0 <= w2)      { vx = V3[0][0]; vy = V3[1][0]; vz = V3[2][0]; }
    else if (w1 <= w2)             { vx = V3[0][1]; vy = V3[1][1]; vz = V3[2][1]; }
    else                           { vx = V3[0][2]; vy = V3[1][2]; vz = V3[2][2]; }
    double Mv0 = M00 * vx + M01 * vy + M02 * vz;
    double Mv1 = M10 * vx + M11 * vy + M12 * vz;
    double Mv2 = M20 * vx + M21 * vy + M22 * vz;
    double F200 = M00 - Mv0 * vx, F201 = M01 - Mv0 * vy, F202 = M02 - Mv0 * vz;
    double F210 = M10 - Mv1 * vx, F211 = M11 - Mv1 * vy, F212 = M12 - Mv1 * vz;
    double F220 = M20 - Mv2 * vx, F221 = M21 - Mv2 * vy, F222 = M22 - Mv2 * vz;
    double R00 = s2 * F200, R01 = s2 * F201, R02 = s2 * F202;
    double R10 = s2 * F210, R11 = s2 * F211, R12 = s2 * F212;
    double R20 = -s2 * m2x * F200 - s2 * m2y * F210 + F220;
    double R21 = -s2 * m2x * F201 - s2 * m2y * F211 + F221;
    double R22 = -s2 * m2x * F202 - s2 * m2y * F212 + F222;
    double D00 = s1 * R00, D10 = s1 * R10, D20 = s1 * R20;
    double D01 = s1 * R01, D11 = s1 * R11, D21 = s1 * R21;
    double D02 = -s1 * m1x * R00 - s1 * m1y * R01 + R02;
    double D12 = -s1 * m1x * R10 - s1 * m1y * R11 + R12;
    double D22 = -s1 * m1x * R20 - s1 * m1y * R21 + R22;
    Fout[0] = D00 / D22; Fout[1] = D01 / D22; Fout[2] = D02 / D22;
    Fout[3] = D10 / D22; Fout[4] = D11 / D22; Fout[5] = D12 / D22;
    Fout[6] = D20 / D22; Fout[7] = D21 / D22; Fout[8] = D22 / D22;
  }
}

// ---------------------------------------------------------------------------
// Kernel 3: cost matrix (unchanged)
// ---------------------------------------------------------------------------
__global__ __launch_bounds__(256) void cost_kernel(
    const float* __restrict__ feat1,
    const float* __restrict__ feat2,
    const float* __restrict__ pts1,
    const float* __restrict__ pts2,
    const double* __restrict__ Fd,
    float* __restrict__ Cout) {
  __shared__ float D1[128][68];
  __shared__ float D2[128][68];
  __shared__ float a0s[64], a1s[64], a2s[64], p2xs[64], p2ys[64];
  const int tid = threadIdx.x;
  const int rowbase = blockIdx.y * 64;
  const int colbase = blockIdx.x * 64;
#pragma unroll
  for (int it = 0; it < 32; ++it) {
    int idx = it * 256 + tid;
    int r = idx >> 7, k = idx & 127;
    D1[k][r] = feat1[(size_t)(rowbase + r) * FEAT + 2 + k];
    D2[k][r] = feat2[(size_t)(colbase + r) * FEAT + 2 + k];
  }
  if (tid < 64) {
    float x1 = pts1[2 * (rowbase + tid)], y1 = pts1[2 * (rowbase + tid) + 1];
    a0s[tid] = (float)(Fd[0] * x1 + Fd[3] * y1 + Fd[6]);
    a1s[tid] = (float)(Fd[1] * x1 + Fd[4] * y1 + Fd[7]);
    a2s[tid] = (float)(Fd[2] * x1 + Fd[5] * y1 + Fd[8]);
    p2xs[tid] = pts2[2 * (colbase + tid)];
    p2ys[tid] = pts2[2 * (colbase + tid) + 1];
  }
  __syncthreads();
  const int tx = tid & 15, ty = tid >> 4;
  float acc[4][4] = {};
#pragma unroll 4
  for (int k = 0; k < 128; ++k) {
    float4 av = *(const float4*)&D1[k][ty * 4];
    float4 bv = *(const float4*)&D2[k][tx * 4];
    float ar[4] = {av.x, av.y, av.z, av.w};
    float br[4] = {bv.x, bv.y, bv.z, bv.w};
#pragma unroll
    for (int r = 0; r < 4; ++r)
#pragma unroll
      for (int c = 0; c < 4; ++c)
        acc[r][c] += fabsf(ar[r] - br[c]);
  }
#pragma unroll
  for (int r = 0; r < 4; ++r) {
    int row = rowbase + ty * 4 + r;
    float a0 = a0s[ty * 4 + r], a1 = a1s[ty * 4 + r], a2 = a2s[ty * 4 + r];
    float4 o;
    float* op = &o.x;
#pragma unroll
    for (int c = 0; c < 4; ++c) {
      float kp = fabsf(a0 * p2xs[tx * 4 + c] + a1 * p2ys[tx * 4 + c] + a2);
      op[c] = acc[r][c] + kp;
    }
    *(float4*)&Cout[(size_t)row * BN + colbase + tx * 4] = o;
  }
}

// ---------------------------------------------------------------------------
// Kernel 4: LAPJV — row reduction + residual column reduction + claims +
// budget-capped augmenting row reduction (2 passes) + SAP for leftovers.
// One wave per batch; solver state in registers (lane L owns cols/rows
// 4L..4L+3); u duals in f64 LDS (ARR-maintained) + register column mirrors.
// Every phase preserves dual feasibility (c-u-v>=0) and tightness of matched
// edges => terminal complete tight matching is optimal; unique f64 optimum
// => result == scipy. ARR runs on the doubly-reduced residual (noise-like;
// R4 showed ARR on the raw near-additive matrix diverges) with budget 1024.
// ---------------------------------------------------------------------------
#define NROWS_C 152
#define ARR_BUDGET 1024

__device__ __forceinline__ unsigned long long sortkey(double d) {
  long long b = __double_as_longlong(d);
  long long m = (b >> 63) | (long long)0x8000000000000000LL;
  return (unsigned long long)(b ^ m);
}
__device__ __forceinline__ double unsortkey(unsigned long long k) {
  unsigned long long m = ((long long)k < 0) ? 0x8000000000000000ULL
                                            : 0xFFFFFFFFFFFFFFFFULL;
  return __longlong_as_double((long long)(k ^ m));
}

template<int CTRL>
__device__ __forceinline__ unsigned long long dppmin(unsigned long long x) {
  int lo = (int)(unsigned)(x & 0xFFFFFFFFULL);
  int hi = (int)(unsigned)(x >> 32);
  int lo2 = __builtin_amdgcn_update_dpp(0, lo, CTRL, 0xF, 0xF, true);
  int hi2 = __builtin_amdgcn_update_dpp(0, hi, CTRL, 0xF, 0xF, true);
  unsigned long long y =
      ((unsigned long long)(unsigned)hi2 << 32) | (unsigned)lo2;
  return y < x ? y : x;
}

template<int CTRL>
__device__ __forceinline__ unsigned dppmin32(unsigned x) {
  int y = __builtin_amdgcn_update_dpp(0, (int)x, CTRL, 0xF, 0xF, true);
  unsigned u = (unsigned)y;
  return u < x ? u : x;
}

__device__ __forceinline__ double rl64(double x, int l) {
  long long bb = __double_as_longlong(x);
  int lo = __builtin_amdgcn_readlane((int)(bb & 0xFFFFFFFFLL), l);
  int hi = __builtin_amdgcn_readlane((int)(bb >> 32), l);
  return __longlong_as_double(((long long)hi << 32) | (unsigned)lo);
}

__device__ __forceinline__ unsigned long long rdpair(unsigned ghi, unsigned glo, int l) {
  return ((unsigned long long)(unsigned)__builtin_amdgcn_readlane((int)ghi, l) << 32)
       | (unsigned)__builtin_amdgcn_readlane((int)glo, l);
}

struct RPick { unsigned long long g; int wl; int li; };

// min over 64 lane-min u64 keys; fast path reduces top-32 (monotone); rare
// hi-tie falls back to exact u64. Winner = lowest lane (= lowest column).
__device__ __forceinline__ RPick reduce_pick(unsigned long long kl, int myli) {
  unsigned hi = (unsigned)(kl >> 32);
  unsigned h = dppmin32<0x121>(hi);
  h = dppmin32<0x122>(h);
  h = dppmin32<0x124>(h);
  h = dppmin32<0x128>(h);
  unsigned g0 = (unsigned)__builtin_amdgcn_readlane((int)h, 0);
  unsigned g1 = (unsigned)__builtin_amdgcn_readlane((int)h, 16);
  unsigned g2 = (unsigned)__builtin_amdgcn_readlane((int)h, 32);
  unsigned g3 = (unsigned)__builtin_amdgcn_readlane((int)h, 48);
  unsigned ga = g0 < g1 ? g0 : g1, gb = g2 < g3 ? g2 : g3;
  unsigned mh = ga < gb ? ga : gb;
  unsigned long long bal = __ballot(hi == mh);
  unsigned long long g; int wl;
  if (__builtin_popcountll(bal) == 1) {
    wl = (int)__builtin_ctzll(bal);
    g = rdpair((unsigned)(kl >> 32), (unsigned)kl, wl);
  } else {
    unsigned long long gg = dppmin<0x121>(kl);
    gg = dppmin<0x122>(gg); gg = dppmin<0x124>(gg); gg = dppmin<0x128>(gg);
    unsigned glo2 = (unsigned)gg, ghi2 = (unsigned)(gg >> 32);
    unsigned long long r0 = rdpair(ghi2, glo2, 0);
    unsigned long long r1 = rdpair(ghi2, glo2, 16);
    unsigned long long r2 = rdpair(ghi2, glo2, 32);
    unsigned long long r3 = rdpair(ghi2, glo2, 48);
    unsigned long long ra = r0 < r1 ? r0 : r1, rb = r2 < r3 ? r2 : r3;
    g = ra < rb ? ra : rb;
    bal = __ballot(kl == g);
    wl = (int)__builtin_ctzll(bal);
  }
  int li = __builtin_amdgcn_readlane(myli, wl);
  RPick r; r.g = g; r.wl = wl; r.li = li; return r;
}

// relax: d = (base + c) - v, base = minval - u[i] (wave-uniform). Strict <.
#define UPD(K, CK, KK, PP) {                                           \
  double d_ = (base + (double)(CK)) - v##K;                            \
  unsigned long long nk_ = sortkey(d_);                                \
  bool a_ = ((rem >> (K)) & 1u) && (nk_ < (KK));                       \
  (KK) = a_ ? nk_ : (KK);                                              \
  (PP) = a_ ? i : (PP); }

#define ROWLOAD(I) ((I) < NROWS_C ? *(const float4*)&rcache[(I)][lane * 4]   \
                                  : *(const float4*)(Cb + (size_t)(I) * BN + lane * 4))

#define R4C_OF(LI) ((LI) == 0 ? r4c0 : (LI) == 1 ? r4c1 : (LI) == 2 ? r4c2 : r4c3)
#define U4_OF(LI)  ((LI) == 0 ? u40  : (LI) == 1 ? u41  : (LI) == 2 ? u42  : u43)

__global__ __launch_bounds__(64) void hungarian_kernel(
    const float* __restrict__ C, float* __restrict__ out_matches) {
  const int b = blockIdx.x;
  const int lane = threadIdx.x;
  __shared__ float rcache[NROWS_C][NN];   // 155648 B
  __shared__ int c4r_lds[NN];             // 1024 B (claims + list build)
  __shared__ double u_sd[NN];             // 2048 B (f64 row duals)
  __shared__ int flistA[NN];              // 1024 B
  __shared__ int flistB[NN];              // 1024 B
  __shared__ int nfc;
  const float* Cb = C + (size_t)b * NN * BN + (size_t)b * NN;

  for (int t = lane; t < NROWS_C * (NN / 4); t += 64) {
    int r = t >> 6, q = t & 63;
    *(float4*)&rcache[r][q * 4] = *(const float4*)(Cb + (size_t)r * BN + q * 4);
  }
  for (int r = lane; r < NN; r += 64) c4r_lds[r] = -1;
  if (lane == 0) nfc = 0;
  __syncthreads();

  // ---- row reduction: u[i] = min_j C[i][j] --------------------------------
  for (int i = 0; i < NN; ++i) {
    float4 cr = ROWLOAD(i);
    float m01 = fminf(cr.x, cr.y), m23 = fminf(cr.z, cr.w);
    unsigned fb = __float_as_uint(fminf(m01, m23));
    fb = dppmin32<0x121>(fb); fb = dppmin32<0x122>(fb);
    fb = dppmin32<0x124>(fb); fb = dppmin32<0x128>(fb);
    unsigned g0 = (unsigned)__builtin_amdgcn_readlane((int)fb, 0);
    unsigned g1 = (unsigned)__builtin_amdgcn_readlane((int)fb, 16);
    unsigned g2 = (unsigned)__builtin_amdgcn_readlane((int)fb, 32);
    unsigned g3 = (unsigned)__builtin_amdgcn_readlane((int)fb, 48);
    unsigned ga = g0 < g1 ? g0 : g1, gb = g2 < g3 ? g2 : g3;
    unsigned gm = ga < gb ? ga : gb;
    if (lane == 0) u_sd[i] = (double)__uint_as_float(gm);
  }
  __syncthreads();

  // ---- column reduction on residual: v[j] = min_i (C[i][j] - u[i]) --------
  double cm0 = DBL_MAX, cm1 = DBL_MAX, cm2 = DBL_MAX, cm3 = DBL_MAX;
  int am0 = 0, am1 = 0, am2 = 0, am3 = 0;
  for (int i = 0; i < NN; ++i) {
    float4 cr = ROWLOAD(i);
    double uu = u_sd[i];
    double s0 = (double)cr.x - uu; if (s0 < cm0) { cm0 = s0; am0 = i; }
    double s1 = (double)cr.y - uu; if (s1 < cm1) { cm1 = s1; am1 = i; }
    double s2 = (double)cr.z - uu; if (s2 < cm2) { cm2 = s2; am2 = i; }
    double s3 = (double)cr.w - uu; if (s3 < cm3) { cm3 = s3; am3 = i; }
  }
  double v0 = cm0, v1 = cm1, v2 = cm2, v3 = cm3;

  // ---- claim tight argmin rows --------------------------------------------
  int r4c0, r4c1, r4c2, r4c3;
  { int old = atomicCAS(&c4r_lds[am0], -1, lane * 4 + 0); r4c0 = (old == -1) ? am0 : -1; }
  { int old = atomicCAS(&c4r_lds[am1], -1, lane * 4 + 1); r4c1 = (old == -1) ? am1 : -1; }
  { int old = atomicCAS(&c4r_lds[am2], -1, lane * 4 + 2); r4c2 = (old == -1) ? am2 : -1; }
  { int old = atomicCAS(&c4r_lds[am3], -1, lane * 4 + 3); r4c3 = (old == -1) ? am3 : -1; }
  __syncthreads();
  // c4r_lds[r] currently holds the claiming column of row r (or -1)
  int c4r0 = c4r_lds[lane * 4 + 0];
  int c4r1 = c4r_lds[lane * 4 + 1];
  int c4r2 = c4r_lds[lane * 4 + 2];
  int c4r3 = c4r_lds[lane * 4 + 3];
  double u40 = (r4c0 >= 0) ? u_sd[r4c0] : 0.0;   // u-mirror of row r4c_k
  double u41 = (r4c1 >= 0) ? u_sd[r4c1] : 0.0;
  double u42 = (r4c2 >= 0) ? u_sd[r4c2] : 0.0;
  double u43 = (r4c3 >= 0) ? u_sd[r4c3] : 0.0;

  // ---- free-row list ------------------------------------------------------
  for (int r = lane; r < NN; r += 64)
    if (c4r_lds[r] < 0) { int p = atomicAdd(&nfc, 1); flistA[p] = r; }
  __syncthreads();
  int cnt_in = nfc;

  const unsigned long long KMAX = 0xFFFFFFFFFFFFFFFFULL;

  // ---- augmenting row reduction (2 passes, budget-capped) -----------------
  {
    int budget = ARR_BUDGET;
    int* curl = flistA;
    int* nextl = flistB;
    for (int pass = 0; pass < 2 && budget > 0; ++pass) {
      int outn = 0;
      for (int k = 0; k < cnt_in && budget > 0; ++k) {
        int i = curl[k];
        bool chain = true;
        while (chain) {
          if (--budget < 0) { chain = false; break; }
          double uii = u_sd[i];
          float4 cr = ROWLOAD(i);
          unsigned long long k0 = sortkey(((double)cr.x - uii) - v0);
          unsigned long long k1 = sortkey(((double)cr.y - uii) - v1);
          unsigned long long k2 = sortkey(((double)cr.z - uii) - v2);
          unsigned long long k3 = sortkey(((double)cr.w - uii) - v3);
          unsigned long long m01 = k0 < k1 ? k0 : k1;
          unsigned long long m23 = k2 < k3 ? k2 : k3;
          unsigned long long kl = m01 < m23 ? m01 : m23;
          int myli = (k0 == kl) ? 0 : (k1 == kl) ? 1 : (k2 == kl) ? 2 : 3;
          RPick a = reduce_pick(kl, myli);
          unsigned long long q0 = k0, q1 = k1, q2 = k2, q3 = k3;
          if (lane == a.wl) {
            if (a.li == 0) q0 = KMAX; else if (a.li == 1) q1 = KMAX;
            else if (a.li == 2) q2 = KMAX; else q3 = KMAX;
          }
          unsigned long long n01 = q0 < q1 ? q0 : q1;
          unsigned long long n23 = q2 < q3 ? q2 : q3;
          unsigned long long kl2 = n01 < n23 ? n01 : n23;
          int myli2 = (q0 == kl2) ? 0 : (q1 == kl2) ? 1 : (q2 == kl2) ? 2 : 3;
          RPick s2 = reduce_pick(kl2, myli2);
          double umin = unsortkey(a.g), usub = unsortkey(s2.g);
          bool strict = (a.g < s2.g);
          int mr1 = R4C_OF(a.li);
          int own1 = __builtin_amdgcn_readlane(mr1, a.wl);
          int jsel, disp;
          if (strict || own1 < 0) {
            jsel = a.wl * 4 + a.li;
            disp = own1;
          } else {
            jsel = s2.wl * 4 + s2.li;
            int mr2 = R4C_OF(s2.li);
            disp = __builtin_amdgcn_readlane(mr2, s2.wl);
          }
          if (strict && lane == a.wl) {
            double dec = usub - umin;
            if (a.li == 0) v0 -= dec; else if (a.li == 1) v1 -= dec;
            else if (a.li == 2) v2 -= dec; else v3 -= dec;
          }
          double unew = uii + usub;   // tight at jsel in both cases
          { int ow = jsel >> 2, sl = jsel & 3;
            if (lane == ow) {
              if (sl == 0)      { r4c0 = i; u40 = unew; }
              else if (sl == 1) { r4c1 = i; u41 = unew; }
              else if (sl == 2) { r4c2 = i; u42 = unew; }
              else              { r4c3 = i; u43 = unew; }
            } }
          { int ow = i >> 2, sl = i & 3;
            if (lane == ow) {
              if (sl == 0) c4r0 = jsel; else if (sl == 1) c4r1 = jsel;
              else if (sl == 2) c4r2 = jsel; else c4r3 = jsel;
            } }
          if (lane == 0) u_sd[i] = unew;
          if (disp >= 0) {
            int ow = disp >> 2, sl = disp & 3;
            if (lane == ow) {
              if (sl == 0) c4r0 = -1; else if (sl == 1) c4r1 = -1;
              else if (sl == 2) c4r2 = -1; else c4r3 = -1;
            }
            if (strict) {
              i = disp;                       // continue chain immediately
            } else {
              if (lane == 0) nextl[outn] = disp;
              outn++;
              chain = false;
            }
          } else chain = false;
        }
      }
      int* tmp = curl; curl = nextl; nextl = tmp;
      cnt_in = outn;
    }
  }

  // ---- shortest augmenting path for remaining free rows -------------------
  for (int cur = 0; cur < NN; ++cur) {
    {
      int sl = cur & 3, ow = cur >> 2;
      int myc = (sl == 0) ? c4r0 : (sl == 1) ? c4r1 : (sl == 2) ? c4r2 : c4r3;
      if (__builtin_amdgcn_readlane(myc, ow) >= 0) continue;
    }
    unsigned long long k0 = KMAX, k1 = KMAX, k2 = KMAX, k3 = KMAX;
    int p0 = -1, p1 = -1, p2 = -1, p3 = -1;
    double shp0 = 0, shp1 = 0, shp2 = 0, shp3 = 0;  // shortest at pop time
    unsigned rem = 0xFu;
    double minval = 0.0;
    const double ucur0 = u_sd[cur];
    double ui = ucur0;
    int i = cur;
    int sink = -1;
    while (true) {
      float4 cr = ROWLOAD(i);
      double base = minval - ui;
      UPD(0, cr.x, k0, p0)
      UPD(1, cr.y, k1, p1)
      UPD(2, cr.z, k2, p2)
      UPD(3, cr.w, k3, p3)
      unsigned long long m01 = k0 < k1 ? k0 : k1;
      unsigned long long m23 = k2 < k3 ? k2 : k3;
      unsigned long long kl = m01 < m23 ? m01 : m23;
      int myli = (k0 == kl) ? 0 : (k1 == kl) ? 1 : (k2 == kl) ? 2 : 3;
      RPick rm = reduce_pick(kl, myli);
      minval = unsortkey(rm.g);
      int jpos = rm.wl * 4 + rm.li;
      int mr = R4C_OF(rm.li);
      int rc = __builtin_amdgcn_readlane(mr, rm.wl);
      double mu = U4_OF(rm.li);
      if (lane == rm.wl) {
        if (rm.li == 0)      { k0 = KMAX; shp0 = minval; }
        else if (rm.li == 1) { k1 = KMAX; shp1 = minval; }
        else if (rm.li == 2) { k2 = KMAX; shp2 = minval; }
        else                 { k3 = KMAX; shp3 = minval; }
        rem &= ~(1u << rm.li);
      }
      if (rc < 0) { sink = jpos; break; }
      ui = rl64(mu, rm.wl);
      i = rc;
    }
    // dual updates (scanned columns; sink included with exact-zero delta)
    if (!(rem & 1u)) { double dl = minval - shp0; v0 -= dl; if (r4c0 >= 0) u40 += dl; }
    if (!(rem & 2u)) { double dl = minval - shp1; v1 -= dl; if (r4c1 >= 0) u41 += dl; }
    if (!(rem & 4u)) { double dl = minval - shp2; v2 -= dl; if (r4c2 >= 0) u42 += dl; }
    if (!(rem & 8u)) { double dl = minval - shp3; v3 -= dl; if (r4c3 >= 0) u43 += dl; }
    // augment along the alternating path; maintain (r4c, u4c, c4r) mirrors
    int j = sink;
    while (true) {
      int slot = j & 3, ow = j >> 2;
      int myp = (slot == 0) ? p0 : (slot == 1) ? p1 : (slot == 2) ? p2 : p3;
      int i2 = __builtin_amdgcn_readlane(myp, ow);
      int s2 = i2 & 3, ow2 = i2 >> 2;
      int myc = (s2 == 0) ? c4r0 : (s2 == 1) ? c4r1 : (s2 == 2) ? c4r2 : c4r3;
      int jn = __builtin_amdgcn_readlane(myc, ow2);  // old col4row[i2] (-1 iff i2==cur)
      double newu;
      if (i2 == cur) {
        newu = ucur0 + minval;                       // u[cur] += minval
      } else {
        int slj = jn & 3, owj = jn >> 2;
        double myuj = (slj == 0) ? u40 : (slj == 1) ? u41
                    : (slj == 2) ? u42 : u43;
        newu = rl64(myuj, owj);                      // u[i2] post-dual-update
      }
      if (lane == ow) {
        if (slot == 0) { r4c0 = i2; u40 = newu; }
        else if (slot == 1) { r4c1 = i2; u41 = newu; }
        else if (slot == 2) { r4c2 = i2; u42 = newu; }
        else { r4c3 = i2; u43 = newu; }
      }
      if (lane == ow2) {
        if (s2 == 0) c4r0 = j; else if (s2 == 1) c4r1 = j;
        else if (s2 == 2) c4r2 = j; else c4r3 = j;
      }
      if (i2 == cur) break;
      j = jn;
    }
  }

  float4 ridx, cidx;
  ridx.x = (float)(lane * 4 + 0); ridx.y = (float)(lane * 4 + 1);
  ridx.z = (float)(lane * 4 + 2); ridx.w = (float)(lane * 4 + 3);
  cidx.x = (float)c4r0; cidx.y = (float)c4r1;
  cidx.z = (float)c4r2; cidx.w = (float)c4r3;
  *(float4*)&out_matches[b * 2 * NN + lane * 4] = ridx;
  *(float4*)&out_matches[b * 2 * NN + NN + lane * 4] = cidx;
}

// ---------------------------------------------------------------------------
extern "C" void kernel_launch(void* const* d_in, const int* in_sizes, int n_in,
                              void* d_out, int out_size, void* d_ws, size_t ws_size,
                              hipStream_t stream) {
  const float* theta = (const float*)d_in[0];
  const float* feat1 = (const float*)d_in[1];   // my_feature
  const float* feat2 = (const float*)d_in[2];   // my_tf_feature
  const int* wp = (const int*)d_in[3];
  const int* hp = (const int*)d_in[4];
  float* out = (float*)d_out;

  float* pts1 = (float*)d_ws;                  // 4096 floats
  float* pts2 = pts1 + 2 * BN;                 // 4096 floats
  double* Fd = (double*)(pts2 + 2 * BN);       // 9 doubles

  prep_kernel<<<BN / 256, 256, 0, stream>>>(theta, feat1, feat2, wp, hp, pts1, pts2);
  fmat_kernel<<<1, 256, 0, stream>>>(pts1, pts2, Fd);
  dim3 grid(BN / 64, BN / 64);
  cost_kernel<<<grid, 256, 0, stream>>>(feat1, feat2, pts1, pts2, Fd, out);
  hungarian_kernel<<<BB, 64, 0, stream>>>(out, out + (size_t)BN * BN);
}

// Round 7
// 2013.315 us; speedup vs baseline: 1.0253x; 1.0253x over previous
//
#include <hip/hip_runtime.h>
#include <hip/hip_bf16.h>
#include <cfloat>
#include <math.h>

// Problem constants
#define BB 8
#define NN 256
#define BN 2048           // B*N
#define DD 128            // descriptor dim
#define FEAT 130          // 2 + 128

// ---------------------------------------------------------------------------
// Kernel 1: point prep (unchanged)
// ---------------------------------------------------------------------------
__global__ __launch_bounds__(256) void prep_kernel(
    const float* __restrict__ theta,
    const float* __restrict__ feat1,   // my_feature   (BN,130)
    const float* __restrict__ feat2,   // my_tf_feature(BN,130)
    const int* __restrict__ wp, const int* __restrict__ hp,
    float* __restrict__ pts1, float* __restrict__ pts2) {
  int i = blockIdx.x * 256 + threadIdx.x;
  if (i >= BN) return;
  double W = (double)wp[0], H = (double)hp[0];
  double th = (double)theta[0];
  double c = cos(th), s = sin(th);
  double kx = (double)feat1[(size_t)i * FEAT + 0];
  double ky = (double)feat1[(size_t)i * FEAT + 1];
  double x = kx - 0.5 * W;
  double y = -ky + 0.5 * H;
  double calx = rint(c * x - s * y);   // jnp.round == round-half-even == rint
  double caly = rint(s * x + c * y);
  double ox = calx + 0.5 * W;
  double oy = -caly + 0.5 * H;
  pts2[2 * i]     = (float)(int)ox;    // astype(int32): trunc toward zero
  pts2[2 * i + 1] = (float)(int)oy;
  pts1[2 * i]     = (float)(int)feat2[(size_t)i * FEAT + 0];
  pts1[2 * i + 1] = (float)(int)feat2[(size_t)i * FEAT + 1];
}

// ---------------------------------------------------------------------------
// Kernel 2: fundamental 8-point (f64), unchanged (passing).
// ---------------------------------------------------------------------------
__device__ inline double wred(double x) {
#pragma unroll
  for (int off = 32; off > 0; off >>= 1) x += __shfl_down(x, off, 64);
  return x;
}

#define JROT(P, Q) {                                                          \
  double app_ = __shfl(Bc[P], P);                                             \
  double aqq_ = __shfl(Bc[Q], Q);                                             \
  double apq_ = __shfl(Bc[P], Q);                                             \
  double c_, s_;                                                              \
  if (fabs(apq_) > 1e-300) {                                                  \
    double tau_ = (aqq_ - app_) / (2.0 * apq_);                               \
    double t_ = (tau_ >= 0.0 ? 1.0 : -1.0) / (fabs(tau_) + sqrt(1.0 + tau_ * tau_)); \
    c_ = 1.0 / sqrt(1.0 + t_ * t_);                                           \
    s_ = t_ * c_;                                                             \
  } else { c_ = 1.0; s_ = 0.0; }                                              \
  const int prt_ = (jln == P) ? Q : ((jln == Q) ? P : jln);                   \
  const bool isP_ = (jln == P), isQ_ = (jln == Q);                            \
  _Pragma("unroll")                                                           \
  for (int ii = 0; ii < 9; ++ii) {                                            \
    double ob_ = __shfl(Bc[ii], prt_);                                        \
    double ov_ = __shfl(Vc[ii], prt_);                                        \
    if (isP_) { Bc[ii] = c_ * Bc[ii] - s_ * ob_; Vc[ii] = c_ * Vc[ii] - s_ * ov_; } \
    if (isQ_) { Bc[ii] = s_ * ob_ + c_ * Bc[ii]; Vc[ii] = s_ * ov_ + c_ * Vc[ii]; } \
  }                                                                           \
  { double rp_ = Bc[P], rq_ = Bc[Q];                                          \
    Bc[P] = c_ * rp_ - s_ * rq_; Bc[Q] = s_ * rp_ + c_ * rq_; } }

#define ROT3(P, Q) {                                                          \
  double apq_ = A3[P][Q];                                                     \
  double c_, s_;                                                              \
  if (fabs(apq_) > 1e-300) {                                                  \
    double tau_ = (A3[Q][Q] - A3[P][P]) / (2.0 * apq_);                       \
    double t_ = (tau_ >= 0.0 ? 1.0 : -1.0) / (fabs(tau_) + sqrt(1.0 + tau_ * tau_)); \
    c_ = 1.0 / sqrt(1.0 + t_ * t_); s_ = t_ * c_;                             \
  } else { c_ = 1.0; s_ = 0.0; }                                              \
  _Pragma("unroll")                                                           \
  for (int ii = 0; ii < 3; ++ii) { double a_ = A3[ii][P], b_ = A3[ii][Q];     \
    A3[ii][P] = c_ * a_ - s_ * b_; A3[ii][Q] = s_ * a_ + c_ * b_; }           \
  _Pragma("unroll")                                                           \
  for (int ii = 0; ii < 3; ++ii) { double a_ = A3[P][ii], b_ = A3[Q][ii];     \
    A3[P][ii] = c_ * a_ - s_ * b_; A3[Q][ii] = s_ * a_ + c_ * b_; }           \
  _Pragma("unroll")                                                           \
  for (int ii = 0; ii < 3; ++ii) { double a_ = V3[ii][P], b_ = V3[ii][Q];     \
    V3[ii][P] = c_ * a_ - s_ * b_; V3[ii][Q] = s_ * a_ + c_ * b_; } }

__global__ __launch_bounds__(256) void fmat_kernel(
    const float* __restrict__ pts1f, const float* __restrict__ pts2f,
    double* __restrict__ Fout) {
  __shared__ double sred[6];
  __shared__ double sATA[45];
  __shared__ double sV[9][16];
  __shared__ double sEv[16];
  const int tid = threadIdx.x;
  const int lane = tid & 63;
  if (tid < 6) sred[tid] = 0.0;
  if (tid < 45) sATA[tid] = 0.0;
  __syncthreads();

  double sx1 = 0, sy1 = 0, sx2 = 0, sy2 = 0;
  for (int p = tid; p < BN; p += 256) {
    sx1 += (double)pts1f[2 * p];     sy1 += (double)pts1f[2 * p + 1];
    sx2 += (double)pts2f[2 * p];     sy2 += (double)pts2f[2 * p + 1];
  }
  sx1 = wred(sx1); sy1 = wred(sy1); sx2 = wred(sx2); sy2 = wred(sy2);
  if (lane == 0) {
    atomicAdd(&sred[0], sx1); atomicAdd(&sred[1], sy1);
    atomicAdd(&sred[2], sx2); atomicAdd(&sred[3], sy2);
  }
  __syncthreads();
  const double m1x = sred[0] * (1.0 / BN), m1y = sred[1] * (1.0 / BN);
  const double m2x = sred[2] * (1.0 / BN), m2y = sred[3] * (1.0 / BN);

  double d1 = 0, d2 = 0;
  for (int p = tid; p < BN; p += 256) {
    double ax = (double)pts1f[2 * p] - m1x, ay = (double)pts1f[2 * p + 1] - m1y;
    double bx = (double)pts2f[2 * p] - m2x, by = (double)pts2f[2 * p + 1] - m2y;
    d1 += sqrt(ax * ax + ay * ay);
    d2 += sqrt(bx * bx + by * by);
  }
  d1 = wred(d1); d2 = wred(d2);
  if (lane == 0) { atomicAdd(&sred[4], d1); atomicAdd(&sred[5], d2); }
  __syncthreads();
  const double s1 = sqrt(2.0) / (sred[4] * (1.0 / BN));
  const double s2 = sqrt(2.0) / (sred[5] * (1.0 / BN));

  double acc45[45];
#pragma unroll
  for (int e = 0; e < 45; ++e) acc45[e] = 0.0;
  for (int p = tid; p < BN; p += 256) {
    double u1 = ((double)pts1f[2 * p]     - m1x) * s1;
    double v1 = ((double)pts1f[2 * p + 1] - m1y) * s1;
    double u2 = ((double)pts2f[2 * p]     - m2x) * s2;
    double v2 = ((double)pts2f[2 * p + 1] - m2y) * s2;
    double r[9] = {u2 * u1, u2 * v1, u2, v2 * u1, v2 * v1, v2, u1, v1, 1.0};
#pragma unroll
    for (int a = 0; a < 9; ++a)
#pragma unroll
      for (int b = a; b < 9; ++b)
        acc45[9 * a - (a * (a - 1)) / 2 + (b - a)] += r[a] * r[b];
  }
#pragma unroll
  for (int e = 0; e < 45; ++e) {
    double vv = wred(acc45[e]);
    if (lane == 0) atomicAdd(&sATA[e], vv);
  }
  __syncthreads();

  if (tid < 64) {
    const int jln = tid;
    double Bc[9], Vc[9];
#pragma unroll
    for (int i2 = 0; i2 < 9; ++i2) {
      if (jln < 9) {
        int a = i2 < jln ? i2 : jln;
        int b = i2 < jln ? jln : i2;
        Bc[i2] = sATA[9 * a - (a * (a - 1)) / 2 + (b - a)];
      } else Bc[i2] = 0.0;
      Vc[i2] = (i2 == jln) ? 1.0 : 0.0;
    }
    for (int sw = 0; sw < 7; ++sw) {
      JROT(0,1) JROT(0,2) JROT(0,3) JROT(0,4) JROT(0,5) JROT(0,6) JROT(0,7) JROT(0,8)
      JROT(1,2) JROT(1,3) JROT(1,4) JROT(1,5) JROT(1,6) JROT(1,7) JROT(1,8)
      JROT(2,3) JROT(2,4) JROT(2,5) JROT(2,6) JROT(2,7) JROT(2,8)
      JROT(3,4) JROT(3,5) JROT(3,6) JROT(3,7) JROT(3,8)
      JROT(4,5) JROT(4,6) JROT(4,7) JROT(4,8)
      JROT(5,6) JROT(5,7) JROT(5,8)
      JROT(6,7) JROT(6,8)
      JROT(7,8)
    }
    double ev = 0.0;
#pragma unroll
    for (int i2 = 0; i2 < 9; ++i2) if (jln == i2) ev = Bc[i2];
    if (jln < 9) {
      sEv[jln] = ev;
#pragma unroll
      for (int i2 = 0; i2 < 9; ++i2) sV[i2][jln] = Vc[i2];
    }
  }
  __syncthreads();

  if (tid == 0) {
    int jm = 0; double be = sEv[0];
#pragma unroll
    for (int jj = 1; jj < 9; ++jj) if (sEv[jj] < be) { be = sEv[jj]; jm = jj; }
    double F0[9];
#pragma unroll
    for (int i2 = 0; i2 < 9; ++i2) F0[i2] = sV[i2][jm];
    double M00 = F0[0], M01 = F0[1], M02 = F0[2];
    double M10 = F0[3], M11 = F0[4], M12 = F0[5];
    double M20 = F0[6], M21 = F0[7], M22 = F0[8];
    double A3[3][3], V3[3][3];
    A3[0][0] = M00*M00 + M10*M10 + M20*M20;
    A3[0][1] = M00*M01 + M10*M11 + M20*M21;
    A3[0][2] = M00*M02 + M10*M12 + M20*M22;
    A3[1][1] = M01*M01 + M11*M11 + M21*M21;
    A3[1][2] = M01*M02 + M11*M12 + M21*M22;
    A3[2][2] = M02*M02 + M12*M12 + M22*M22;
    A3[1][0] = A3[0][1]; A3[2][0] = A3[0][2]; A3[2][1] = A3[1][2];
#pragma unroll
    for (int ii = 0; ii < 3; ++ii)
#pragma unroll
      for (int jj = 0; jj < 3; ++jj) V3[ii][jj] = (ii == jj) ? 1.0 : 0.0;
    for (int sw = 0; sw < 10; ++sw) { ROT3(0,1) ROT3(0,2) ROT3(1,2) }
    double w0 = A3[0][0], w1 = A3[1][1], w2 = A3[2][2];
    double vx, vy, vz;
    if (w0 <= w1 && w0 <= w2)      { vx = V3[0][0]; vy = V3[1][0]; vz = V3[2][0]; }
    else if (w1 <= w2)             { vx = V3[0][1]; vy = V3[1][1]; vz = V3[2][1]; }
    else                           { vx = V3[0][2]; vy = V3[1][2]; vz = V3[2][2]; }
    double Mv0 = M00 * vx + M01 * vy + M02 * vz;
    double Mv1 = M10 * vx + M11 * vy + M12 * vz;
    double Mv2 = M20 * vx + M21 * vy + M22 * vz;
    double F200 = M00 - Mv0 * vx, F201 = M01 - Mv0 * vy, F202 = M02 - Mv0 * vz;
    double F210 = M10 - Mv1 * vx, F211 = M11 - Mv1 * vy, F212 = M12 - Mv1 * vz;
    double F220 = M20 - Mv2 * vx, F221 = M21 - Mv2 * vy, F222 = M22 - Mv2 * vz;
    double R00 = s2 * F200, R01 = s2 * F201, R02 = s2 * F202;
    double R10 = s2 * F210, R11 = s2 * F211, R12 = s2 * F212;
    double R20 = -s2 * m2x * F200 - s2 * m2y * F210 + F220;
    double R21 = -s2 * m2x * F201 - s2 * m2y * F211 + F221;
    double R22 = -s2 * m2x * F202 - s2 * m2y * F212 + F222;
    double D00 = s1 * R00, D10 = s1 * R10, D20 = s1 * R20;
    double D01 = s1 * R01, D11 = s1 * R11, D21 = s1 * R21;
    double D02 = -s1 * m1x * R00 - s1 * m1y * R01 + R02;
    double D12 = -s1 * m1x * R10 - s1 * m1y * R11 + R12;
    double D22 = -s1 * m1x * R20 - s1 * m1y * R21 + R22;
    Fout[0] = D00 / D22; Fout[1] = D01 / D22; Fout[2] = D02 / D22;
    Fout[3] = D10 / D22; Fout[4] = D11 / D22; Fout[5] = D12 / D22;
    Fout[6] = D20 / D22; Fout[7] = D21 / D22; Fout[8] = D22 / D22;
  }
}

// ---------------------------------------------------------------------------
// Kernel 3: cost matrix (unchanged)
// ---------------------------------------------------------------------------
__global__ __launch_bounds__(256) void cost_kernel(
    const float* __restrict__ feat1,
    const float* __restrict__ feat2,
    const float* __restrict__ pts1,
    const float* __restrict__ pts2,
    const double* __restrict__ Fd,
    float* __restrict__ Cout) {
  __shared__ float D1[128][68];
  __shared__ float D2[128][68];
  __shared__ float a0s[64], a1s[64], a2s[64], p2xs[64], p2ys[64];
  const int tid = threadIdx.x;
  const int rowbase = blockIdx.y * 64;
  const int colbase = blockIdx.x * 64;
#pragma unroll
  for (int it = 0; it < 32; ++it) {
    int idx = it * 256 + tid;
    int r = idx >> 7, k = idx & 127;
    D1[k][r] = feat1[(size_t)(rowbase + r) * FEAT + 2 + k];
    D2[k][r] = feat2[(size_t)(colbase + r) * FEAT + 2 + k];
  }
  if (tid < 64) {
    float x1 = pts1[2 * (rowbase + tid)], y1 = pts1[2 * (rowbase + tid) + 1];
    a0s[tid] = (float)(Fd[0] * x1 + Fd[3] * y1 + Fd[6]);
    a1s[tid] = (float)(Fd[1] * x1 + Fd[4] * y1 + Fd[7]);
    a2s[tid] = (float)(Fd[2] * x1 + Fd[5] * y1 + Fd[8]);
    p2xs[tid] = pts2[2 * (colbase + tid)];
    p2ys[tid] = pts2[2 * (colbase + tid) + 1];
  }
  __syncthreads();
  const int tx = tid & 15, ty = tid >> 4;
  float acc[4][4] = {};
#pragma unroll 4
  for (int k = 0; k < 128; ++k) {
    float4 av = *(const float4*)&D1[k][ty * 4];
    float4 bv = *(const float4*)&D2[k][tx * 4];
    float ar[4] = {av.x, av.y, av.z, av.w};
    float br[4] = {bv.x, bv.y, bv.z, bv.w};
#pragma unroll
    for (int r = 0; r < 4; ++r)
#pragma unroll
      for (int c = 0; c < 4; ++c)
        acc[r][c] += fabsf(ar[r] - br[c]);
  }
#pragma unroll
  for (int r = 0; r < 4; ++r) {
    int row = rowbase + ty * 4 + r;
    float a0 = a0s[ty * 4 + r], a1 = a1s[ty * 4 + r], a2 = a2s[ty * 4 + r];
    float4 o;
    float* op = &o.x;
#pragma unroll
    for (int c = 0; c < 4; ++c) {
      float kp = fabsf(a0 * p2xs[tx * 4 + c] + a1 * p2ys[tx * 4 + c] + a2);
      op[c] = acc[r][c] + kp;
    }
    *(float4*)&Cout[(size_t)row * BN + colbase + tx * 4] = o;
  }
}

// ---------------------------------------------------------------------------
// Kernel 4: LAP via min-plus dual refinement + tight claims + SAP.
//   u0[i]=rowmin -> v1=min(c-u0) -> u1[i]=min_j(c-v1) -> v2=min(c-u1)+argmin
//   -> CAS claims on tight edges -> SAP (R5 machinery, register state).
// Every phase preserves exact f64 feasibility (c-u-v>=0) and bit-exact
// tightness at claimed pairs; unique f64 optimum => result == scipy.
// ARR reverted (R4/R6: price-increment methods degenerate on this matrix).
// ---------------------------------------------------------------------------
#define NROWS_C 152

__device__ __forceinline__ unsigned long long sortkey(double d) {
  long long b = __double_as_longlong(d);
  long long m = (b >> 63) | (long long)0x8000000000000000LL;
  return (unsigned long long)(b ^ m);
}
__device__ __forceinline__ double unsortkey(unsigned long long k) {
  unsigned long long m = ((long long)k < 0) ? 0x8000000000000000ULL
                                            : 0xFFFFFFFFFFFFFFFFULL;
  return __longlong_as_double((long long)(k ^ m));
}

// DPP min step: old = x so row_mask-disabled / invalid-source lanes are no-ops
template<int CTRL, int RM>
__device__ __forceinline__ unsigned dppm32(unsigned x) {
  int y = __builtin_amdgcn_update_dpp((int)x, (int)x, CTRL, RM, 0xF, false);
  unsigned u = (unsigned)y;
  return u < x ? u : x;
}
template<int CTRL, int RM>
__device__ __forceinline__ unsigned long long dppm64(unsigned long long x) {
  int lo = (int)(unsigned)x, hi = (int)(unsigned)(x >> 32);
  int lo2 = __builtin_amdgcn_update_dpp(lo, lo, CTRL, RM, 0xF, false);
  int hi2 = __builtin_amdgcn_update_dpp(hi, hi, CTRL, RM, 0xF, false);
  unsigned long long y =
      ((unsigned long long)(unsigned)hi2 << 32) | (unsigned)lo2;
  return y < x ? y : x;
}

// scalar (wave-uniform) min of a u32 across 64 lanes: shr-scan + row bcasts
__device__ __forceinline__ unsigned wave_min_u32(unsigned x) {
  unsigned h = dppm32<0x111, 0xF>(x);   // row_shr:1
  h = dppm32<0x112, 0xF>(h);            // row_shr:2
  h = dppm32<0x114, 0xF>(h);            // row_shr:4
  h = dppm32<0x118, 0xF>(h);            // row_shr:8 -> lane15/31/47/63 row mins
  h = dppm32<0x142, 0xA>(h);            // row_bcast15 (rows 1,3)
  h = dppm32<0x143, 0xC>(h);            // row_bcast31 (rows 2,3) -> lane63 all
  return (unsigned)__builtin_amdgcn_readlane((int)h, 63);
}
__device__ __forceinline__ unsigned long long wave_min_u64(unsigned long long x) {
  unsigned long long h = dppm64<0x111, 0xF>(x);
  h = dppm64<0x112, 0xF>(h);
  h = dppm64<0x114, 0xF>(h);
  h = dppm64<0x118, 0xF>(h);
  h = dppm64<0x142, 0xA>(h);
  h = dppm64<0x143, 0xC>(h);
  unsigned lo = (unsigned)__builtin_amdgcn_readlane((int)(unsigned)h, 63);
  unsigned hi = (unsigned)__builtin_amdgcn_readlane((int)(unsigned)(h >> 32), 63);
  return ((unsigned long long)hi << 32) | lo;
}

__device__ __forceinline__ double rl64(double x, int l) {
  long long bb = __double_as_longlong(x);
  int lo = __builtin_amdgcn_readlane((int)(bb & 0xFFFFFFFFLL), l);
  int hi = __builtin_amdgcn_readlane((int)(bb >> 32), l);
  return __longlong_as_double(((long long)hi << 32) | (unsigned)lo);
}
__device__ __forceinline__ unsigned long long rdpair(unsigned ghi, unsigned glo, int l) {
  return ((unsigned long long)(unsigned)__builtin_amdgcn_readlane((int)ghi, l) << 32)
       | (unsigned)__builtin_amdgcn_readlane((int)glo, l);
}

// exact f64 min across lanes (value only); hi-32 fast path, exact fallback
__device__ __forceinline__ unsigned long long reduce_key(unsigned long long kl) {
  unsigned hi = (unsigned)(kl >> 32);
  unsigned mh = wave_min_u32(hi);
  unsigned long long bal = __ballot(hi == mh);
  if (__builtin_popcountll(bal) == 1)
    return rdpair(hi, (unsigned)kl, (int)__builtin_ctzll(bal));
  return wave_min_u64(kl);
}

struct RPick { unsigned long long g; int wl; int li; };

// argmin pick: winner = lowest lane holding the min key (= lowest column)
__device__ __forceinline__ RPick reduce_pick(unsigned long long kl, int myli) {
  unsigned hi = (unsigned)(kl >> 32);
  unsigned mh = wave_min_u32(hi);
  unsigned long long bal = __ballot(hi == mh);
  unsigned long long g; int wl;
  if (__builtin_popcountll(bal) == 1) {
    wl = (int)__builtin_ctzll(bal);
    g = rdpair(hi, (unsigned)kl, wl);
  } else {
    g = wave_min_u64(kl);
    bal = __ballot(kl == g);
    wl = (int)__builtin_ctzll(bal);
  }
  int li = __builtin_amdgcn_readlane(myli, wl);
  RPick r; r.g = g; r.wl = wl; r.li = li; return r;
}

// relax: d = (base + c) - v, base = minval - u[i] (wave-uniform). Strict <.
#define UPD(K, CK, KK, PP) {                                           \
  double d_ = (base + (double)(CK)) - v##K;                            \
  unsigned long long nk_ = sortkey(d_);                                \
  bool a_ = ((rem >> (K)) & 1u) && (nk_ < (KK));                       \
  (KK) = a_ ? nk_ : (KK);                                              \
  (PP) = a_ ? i : (PP); }

#define ROWLOAD(I) ((I) < NROWS_C ? *(const float4*)&rcache[(I)][lane * 4]   \
                                  : *(const float4*)(Cb + (size_t)(I) * BN + lane * 4))

#define R4C_OF(LI) ((LI) == 0 ? r4c0 : (LI) == 1 ? r4c1 : (LI) == 2 ? r4c2 : r4c3)
#define U4_OF(LI)  ((LI) == 0 ? u40  : (LI) == 1 ? u41  : (LI) == 2 ? u42  : u43)

__global__ __launch_bounds__(64) void hungarian_kernel(
    const float* __restrict__ C, float* __restrict__ out_matches) {
  const int b = blockIdx.x;
  const int lane = threadIdx.x;
  __shared__ float rcache[NROWS_C][NN];   // 155648 B
  __shared__ int c4r_lds[NN];             // 1024 B
  __shared__ double u_sd[NN];             // 2048 B (f64 row duals)
  const float* Cb = C + (size_t)b * NN * BN + (size_t)b * NN;

  for (int t = lane; t < NROWS_C * (NN / 4); t += 64) {
    int r = t >> 6, q = t & 63;
    *(float4*)&rcache[r][q * 4] = *(const float4*)(Cb + (size_t)r * BN + q * 4);
  }
  for (int r = lane; r < NN; r += 64) c4r_lds[r] = -1;
  __syncthreads();

  // ---- u0[i] = min_j C[i][j] (exact f32; C >= 0 -> bits monotone) ---------
  for (int i = 0; i < NN; ++i) {
    float4 cr = ROWLOAD(i);
    float m01 = fminf(cr.x, cr.y), m23 = fminf(cr.z, cr.w);
    unsigned gm = wave_min_u32(__float_as_uint(fminf(m01, m23)));
    if (lane == 0) u_sd[i] = (double)__uint_as_float(gm);
  }
  __syncthreads();

  // ---- v1[j] = min_i (C[i][j] - u0[i]) ------------------------------------
  double v0, v1, v2, v3;
  {
    double c0 = DBL_MAX, c1 = DBL_MAX, c2 = DBL_MAX, c3 = DBL_MAX;
    for (int i = 0; i < NN; ++i) {
      float4 cr = ROWLOAD(i);
      double uu = u_sd[i];
      double s0 = (double)cr.x - uu; c0 = s0 < c0 ? s0 : c0;
      double s1 = (double)cr.y - uu; c1 = s1 < c1 ? s1 : c1;
      double s2 = (double)cr.z - uu; c2 = s2 < c2 ? s2 : c2;
      double s3 = (double)cr.w - uu; c3 = s3 < c3 ? s3 : c3;
    }
    v0 = c0; v1 = c1; v2 = c2; v3 = c3;
  }

  // ---- u1[i] = min_j (C[i][j] - v1[j])  (min-plus refinement round) -------
  __syncthreads();
  for (int i = 0; i < NN; ++i) {
    float4 cr = ROWLOAD(i);
    double s0 = (double)cr.x - v0, s1 = (double)cr.y - v1;
    double s2 = (double)cr.z - v2, s3 = (double)cr.w - v3;
    double ma = s0 < s1 ? s0 : s1, mb = s2 < s3 ? s2 : s3;
    unsigned long long kl = sortkey(ma < mb ? ma : mb);
    unsigned long long g = reduce_key(kl);
    if (lane == 0) u_sd[i] = unsortkey(g);
  }
  __syncthreads();

  // ---- v2[j] = min_i (C[i][j] - u1[i]) with argmin ------------------------
  int am0 = 0, am1 = 0, am2 = 0, am3 = 0;
  {
    double c0 = DBL_MAX, c1 = DBL_MAX, c2 = DBL_MAX, c3 = DBL_MAX;
    for (int i = 0; i < NN; ++i) {
      float4 cr = ROWLOAD(i);
      double uu = u_sd[i];
      double s0 = (double)cr.x - uu; if (s0 < c0) { c0 = s0; am0 = i; }
      double s1 = (double)cr.y - uu; if (s1 < c1) { c1 = s1; am1 = i; }
      double s2 = (double)cr.z - uu; if (s2 < c2) { c2 = s2; am2 = i; }
      double s3 = (double)cr.w - uu; if (s3 < c3) { c3 = s3; am3 = i; }
    }
    v0 = c0; v1 = c1; v2 = c2; v3 = c3;
  }

  // ---- claim tight argmin rows (any maximal tight matching is valid) ------
  int r4c0, r4c1, r4c2, r4c3;
  { int old = atomicCAS(&c4r_lds[am0], -1, lane * 4 + 0); r4c0 = (old == -1) ? am0 : -1; }
  { int old = atomicCAS(&c4r_lds[am1], -1, lane * 4 + 1); r4c1 = (old == -1) ? am1 : -1; }
  { int old = atomicCAS(&c4r_lds[am2], -1, lane * 4 + 2); r4c2 = (old == -1) ? am2 : -1; }
  { int old = atomicCAS(&c4r_lds[am3], -1, lane * 4 + 3); r4c3 = (old == -1) ? am3 : -1; }
  __syncthreads();
  int c4r0 = c4r_lds[lane * 4 + 0];
  int c4r1 = c4r_lds[lane * 4 + 1];
  int c4r2 = c4r_lds[lane * 4 + 2];
  int c4r3 = c4r_lds[lane * 4 + 3];
  double u40 = (r4c0 >= 0) ? u_sd[r4c0] : 0.0;   // u-mirror of row r4c_k
  double u41 = (r4c1 >= 0) ? u_sd[r4c1] : 0.0;
  double u42 = (r4c2 >= 0) ? u_sd[r4c2] : 0.0;
  double u43 = (r4c3 >= 0) ? u_sd[r4c3] : 0.0;

  const unsigned long long KMAX = 0xFFFFFFFFFFFFFFFFULL;

  // ---- shortest augmenting path for each free row -------------------------
  for (int cur = 0; cur < NN; ++cur) {
    {
      int sl = cur & 3, ow = cur >> 2;
      int myc = (sl == 0) ? c4r0 : (sl == 1) ? c4r1 : (sl == 2) ? c4r2 : c4r3;
      if (__builtin_amdgcn_readlane(myc, ow) >= 0) continue;
    }
    unsigned long long k0 = KMAX, k1 = KMAX, k2 = KMAX, k3 = KMAX;
    int p0 = -1, p1 = -1, p2 = -1, p3 = -1;
    double shp0 = 0, shp1 = 0, shp2 = 0, shp3 = 0;  // shortest at pop time
    unsigned rem = 0xFu;
    double minval = 0.0;
    const double ucur0 = u_sd[cur];
    double ui = ucur0;
    int i = cur;
    int sink = -1;
    while (true) {
      float4 cr = ROWLOAD(i);
      double base = minval - ui;
      UPD(0, cr.x, k0, p0)
      UPD(1, cr.y, k1, p1)
      UPD(2, cr.z, k2, p2)
      UPD(3, cr.w, k3, p3)
      unsigned long long m01 = k0 < k1 ? k0 : k1;
      unsigned long long m23 = k2 < k3 ? k2 : k3;
      unsigned long long kl = m01 < m23 ? m01 : m23;
      int myli = (k0 == kl) ? 0 : (k1 == kl) ? 1 : (k2 == kl) ? 2 : 3;
      RPick rm = reduce_pick(kl, myli);
      minval = unsortkey(rm.g);
      int jpos = rm.wl * 4 + rm.li;
      int mr = R4C_OF(rm.li);
      int rc = __builtin_amdgcn_readlane(mr, rm.wl);
      double mu = U4_OF(rm.li);
      if (lane == rm.wl) {
        if (rm.li == 0)      { k0 = KMAX; shp0 = minval; }
        else if (rm.li == 1) { k1 = KMAX; shp1 = minval; }
        else if (rm.li == 2) { k2 = KMAX; shp2 = minval; }
        else                 { k3 = KMAX; shp3 = minval; }
        rem &= ~(1u << rm.li);
      }
      if (rc < 0) { sink = jpos; break; }
      ui = rl64(mu, rm.wl);
      i = rc;
    }
    // dual updates (scanned columns; sink included with exact-zero delta)
    if (!(rem & 1u)) { double dl = minval - shp0; v0 -= dl; if (r4c0 >= 0) u40 += dl; }
    if (!(rem & 2u)) { double dl = minval - shp1; v1 -= dl; if (r4c1 >= 0) u41 += dl; }
    if (!(rem & 4u)) { double dl = minval - shp2; v2 -= dl; if (r4c2 >= 0) u42 += dl; }
    if (!(rem & 8u)) { double dl = minval - shp3; v3 -= dl; if (r4c3 >= 0) u43 += dl; }
    // augment along the alternating path; maintain (r4c, u4c, c4r) mirrors
    int j = sink;
    while (true) {
      int slot = j & 3, ow = j >> 2;
      int myp = (slot == 0) ? p0 : (slot == 1) ? p1 : (slot == 2) ? p2 : p3;
      int i2 = __builtin_amdgcn_readlane(myp, ow);
      int s2 = i2 & 3, ow2 = i2 >> 2;
      int myc = (s2 == 0) ? c4r0 : (s2 == 1) ? c4r1 : (s2 == 2) ? c4r2 : c4r3;
      int jn = __builtin_amdgcn_readlane(myc, ow2);  // old col4row[i2] (-1 iff i2==cur)
      double newu;
      if (i2 == cur) {
        newu = ucur0 + minval;                       // u[cur] += minval
      } else {
        int slj = jn & 3, owj = jn >> 2;
        double myuj = (slj == 0) ? u40 : (slj == 1) ? u41
                    : (slj == 2) ? u42 : u43;
        newu = rl64(myuj, owj);                      // u[i2] post-dual-update
      }
      if (lane == ow) {
        if (slot == 0) { r4c0 = i2; u40 = newu; }
        else if (slot == 1) { r4c1 = i2; u41 = newu; }
        else if (slot == 2) { r4c2 = i2; u42 = newu; }
        else { r4c3 = i2; u43 = newu; }
      }
      if (lane == ow2) {
        if (s2 == 0) c4r0 = j; else if (s2 == 1) c4r1 = j;
        else if (s2 == 2) c4r2 = j; else c4r3 = j;
      }
      if (i2 == cur) break;
      j = jn;
    }
  }

  float4 ridx, cidx;
  ridx.x = (float)(lane * 4 + 0); ridx.y = (float)(lane * 4 + 1);
  ridx.z = (float)(lane * 4 + 2); ridx.w = (float)(lane * 4 + 3);
  cidx.x = (float)c4r0; cidx.y = (float)c4r1;
  cidx.z = (float)c4r2; cidx.w = (float)c4r3;
  *(float4*)&out_matches[b * 2 * NN + lane * 4] = ridx;
  *(float4*)&out_matches[b * 2 * NN + NN + lane * 4] = cidx;
}

// ---------------------------------------------------------------------------
extern "C" void kernel_launch(void* const* d_in, const int* in_sizes, int n_in,
                              void* d_out, int out_size, void* d_ws, size_t ws_size,
                              hipStream_t stream) {
  const float* theta = (const float*)d_in[0];
  const float* feat1 = (const float*)d_in[1];   // my_feature
  const float* feat2 = (const float*)d_in[2];   // my_tf_feature
  const int* wp = (const int*)d_in[3];
  const int* hp = (const int*)d_in[4];
  float* out = (float*)d_out;

  float* pts1 = (float*)d_ws;                  // 4096 floats
  float* pts2 = pts1 + 2 * BN;                 // 4096 floats
  double* Fd = (double*)(pts2 + 2 * BN);       // 9 doubles

  prep_kernel<<<BN / 256, 256, 0, stream>>>(theta, feat1, feat2, wp, hp, pts1, pts2);
  fmat_kernel<<<1, 256, 0, stream>>>(pts1, pts2, Fd);
  dim3 grid(BN / 64, BN / 64);
  cost_kernel<<<grid, 256, 0, stream>>>(feat1, feat2, pts1, pts2, Fd, out);
  hungarian_kernel<<<BB, 64, 0, stream>>>(out, out + (size_t)BN * BN);
}

// Round 8
// 1985.435 us; speedup vs baseline: 1.0397x; 1.0140x over previous
//
#include <hip/hip_runtime.h>
#include <hip/hip_bf16.h>
#include <cfloat>
#include <math.h>

// Problem constants
#define BB 8
#define NN 256
#define BN 2048           // B*N
#define DD 128            // descriptor dim
#define FEAT 130          // 2 + 128

// ---------------------------------------------------------------------------
// Kernel 1: point prep (unchanged)
// ---------------------------------------------------------------------------
__global__ __launch_bounds__(256) void prep_kernel(
    const float* __restrict__ theta,
    const float* __restrict__ feat1,   // my_feature   (BN,130)
    const float* __restrict__ feat2,   // my_tf_feature(BN,130)
    const int* __restrict__ wp, const int* __restrict__ hp,
    float* __restrict__ pts1, float* __restrict__ pts2) {
  int i = blockIdx.x * 256 + threadIdx.x;
  if (i >= BN) return;
  double W = (double)wp[0], H = (double)hp[0];
  double th = (double)theta[0];
  double c = cos(th), s = sin(th);
  double kx = (double)feat1[(size_t)i * FEAT + 0];
  double ky = (double)feat1[(size_t)i * FEAT + 1];
  double x = kx - 0.5 * W;
  double y = -ky + 0.5 * H;
  double calx = rint(c * x - s * y);   // jnp.round == round-half-even == rint
  double caly = rint(s * x + c * y);
  double ox = calx + 0.5 * W;
  double oy = -caly + 0.5 * H;
  pts2[2 * i]     = (float)(int)ox;    // astype(int32): trunc toward zero
  pts2[2 * i + 1] = (float)(int)oy;
  pts1[2 * i]     = (float)(int)feat2[(size_t)i * FEAT + 0];
  pts1[2 * i + 1] = (float)(int)feat2[(size_t)i * FEAT + 1];
}

// ---------------------------------------------------------------------------
// Kernel 2: fundamental 8-point (f64), unchanged (passing).
// ---------------------------------------------------------------------------
__device__ inline double wred(double x) {
#pragma unroll
  for (int off = 32; off > 0; off >>= 1) x += __shfl_down(x, off, 64);
  return x;
}

#define JROT(P, Q) {                                                          \
  double app_ = __shfl(Bc[P], P);                                             \
  double aqq_ = __shfl(Bc[Q], Q);                                             \
  double apq_ = __shfl(Bc[P], Q);                                             \
  double c_, s_;                                                              \
  if (fabs(apq_) > 1e-300) {                                                  \
    double tau_ = (aqq_ - app_) / (2.0 * apq_);                               \
    double t_ = (tau_ >= 0.0 ? 1.0 : -1.0) / (fabs(tau_) + sqrt(1.0 + tau_ * tau_)); \
    c_ = 1.0 / sqrt(1.0 + t_ * t_);                                           \
    s_ = t_ * c_;                                                             \
  } else { c_ = 1.0; s_ = 0.0; }                                              \
  const int prt_ = (jln == P) ? Q : ((jln == Q) ? P : jln);                   \
  const bool isP_ = (jln == P), isQ_ = (jln == Q);                            \
  _Pragma("unroll")                                                           \
  for (int ii = 0; ii < 9; ++ii) {                                            \
    double ob_ = __shfl(Bc[ii], prt_);                                        \
    double ov_ = __shfl(Vc[ii], prt_);                                        \
    if (isP_) { Bc[ii] = c_ * Bc[ii] - s_ * ob_; Vc[ii] = c_ * Vc[ii] - s_ * ov_; } \
    if (isQ_) { Bc[ii] = s_ * ob_ + c_ * Bc[ii]; Vc[ii] = s_ * ov_ + c_ * Vc[ii]; } \
  }                                                                           \
  { double rp_ = Bc[P], rq_ = Bc[Q];                                          \
    Bc[P] = c_ * rp_ - s_ * rq_; Bc[Q] = s_ * rp_ + c_ * rq_; } }

#define ROT3(P, Q) {                                                          \
  double apq_ = A3[P][Q];                                                     \
  double c_, s_;                                                              \
  if (fabs(apq_) > 1e-300) {                                                  \
    double tau_ = (A3[Q][Q] - A3[P][P]) / (2.0 * apq_);                       \
    double t_ = (tau_ >= 0.0 ? 1.0 : -1.0) / (fabs(tau_) + sqrt(1.0 + tau_ * tau_)); \
    c_ = 1.0 / sqrt(1.0 + t_ * t_); s_ = t_ * c_;                             \
  } else { c_ = 1.0; s_ = 0.0; }                                              \
  _Pragma("unroll")                                                           \
  for (int ii = 0; ii < 3; ++ii) { double a_ = A3[ii][P], b_ = A3[ii][Q];     \
    A3[ii][P] = c_ * a_ - s_ * b_; A3[ii][Q] = s_ * a_ + c_ * b_; }           \
  _Pragma("unroll")                                                           \
  for (int ii = 0; ii < 3; ++ii) { double a_ = A3[P][ii], b_ = A3[Q][ii];     \
    A3[P][ii] = c_ * a_ - s_ * b_; A3[Q][ii] = s_ * a_ + c_ * b_; }           \
  _Pragma("unroll")                                                           \
  for (int ii = 0; ii < 3; ++ii) { double a_ = V3[ii][P], b_ = V3[ii][Q];     \
    V3[ii][P] = c_ * a_ - s_ * b_; V3[ii][Q] = s_ * a_ + c_ * b_; } }

__global__ __launch_bounds__(256) void fmat_kernel(
    const float* __restrict__ pts1f, const float* __restrict__ pts2f,
    double* __restrict__ Fout) {
  __shared__ double sred[6];
  __shared__ double sATA[45];
  __shared__ double sV[9][16];
  __shared__ double sEv[16];
  const int tid = threadIdx.x;
  const int lane = tid & 63;
  if (tid < 6) sred[tid] = 0.0;
  if (tid < 45) sATA[tid] = 0.0;
  __syncthreads();

  double sx1 = 0, sy1 = 0, sx2 = 0, sy2 = 0;
  for (int p = tid; p < BN; p += 256) {
    sx1 += (double)pts1f[2 * p];     sy1 += (double)pts1f[2 * p + 1];
    sx2 += (double)pts2f[2 * p];     sy2 += (double)pts2f[2 * p + 1];
  }
  sx1 = wred(sx1); sy1 = wred(sy1); sx2 = wred(sx2); sy2 = wred(sy2);
  if (lane == 0) {
    atomicAdd(&sred[0], sx1); atomicAdd(&sred[1], sy1);
    atomicAdd(&sred[2], sx2); atomicAdd(&sred[3], sy2);
  }
  __syncthreads();
  const double m1x = sred[0] * (1.0 / BN), m1y = sred[1] * (1.0 / BN);
  const double m2x = sred[2] * (1.0 / BN), m2y = sred[3] * (1.0 / BN);

  double d1 = 0, d2 = 0;
  for (int p = tid; p < BN; p += 256) {
    double ax = (double)pts1f[2 * p] - m1x, ay = (double)pts1f[2 * p + 1] - m1y;
    double bx = (double)pts2f[2 * p] - m2x, by = (double)pts2f[2 * p + 1] - m2y;
    d1 += sqrt(ax * ax + ay * ay);
    d2 += sqrt(bx * bx + by * by);
  }
  d1 = wred(d1); d2 = wred(d2);
  if (lane == 0) { atomicAdd(&sred[4], d1); atomicAdd(&sred[5], d2); }
  __syncthreads();
  const double s1 = sqrt(2.0) / (sred[4] * (1.0 / BN));
  const double s2 = sqrt(2.0) / (sred[5] * (1.0 / BN));

  double acc45[45];
#pragma unroll
  for (int e = 0; e < 45; ++e) acc45[e] = 0.0;
  for (int p = tid; p < BN; p += 256) {
    double u1 = ((double)pts1f[2 * p]     - m1x) * s1;
    double v1 = ((double)pts1f[2 * p + 1] - m1y) * s1;
    double u2 = ((double)pts2f[2 * p]     - m2x) * s2;
    double v2 = ((double)pts2f[2 * p + 1] - m2y) * s2;
    double r[9] = {u2 * u1, u2 * v1, u2, v2 * u1, v2 * v1, v2, u1, v1, 1.0};
#pragma unroll
    for (int a = 0; a < 9; ++a)
#pragma unroll
      for (int b = a; b < 9; ++b)
        acc45[9 * a - (a * (a - 1)) / 2 + (b - a)] += r[a] * r[b];
  }
#pragma unroll
  for (int e = 0; e < 45; ++e) {
    double vv = wred(acc45[e]);
    if (lane == 0) atomicAdd(&sATA[e], vv);
  }
  __syncthreads();

  if (tid < 64) {
    const int jln = tid;
    double Bc[9], Vc[9];
#pragma unroll
    for (int i2 = 0; i2 < 9; ++i2) {
      if (jln < 9) {
        int a = i2 < jln ? i2 : jln;
        int b = i2 < jln ? jln : i2;
        Bc[i2] = sATA[9 * a - (a * (a - 1)) / 2 + (b - a)];
      } else Bc[i2] = 0.0;
      Vc[i2] = (i2 == jln) ? 1.0 : 0.0;
    }
    for (int sw = 0; sw < 7; ++sw) {
      JROT(0,1) JROT(0,2) JROT(0,3) JROT(0,4) JROT(0,5) JROT(0,6) JROT(0,7) JROT(0,8)
      JROT(1,2) JROT(1,3) JROT(1,4) JROT(1,5) JROT(1,6) JROT(1,7) JROT(1,8)
      JROT(2,3) JROT(2,4) JROT(2,5) JROT(2,6) JROT(2,7) JROT(2,8)
      JROT(3,4) JROT(3,5) JROT(3,6) JROT(3,7) JROT(3,8)
      JROT(4,5) JROT(4,6) JROT(4,7) JROT(4,8)
      JROT(5,6) JROT(5,7) JROT(5,8)
      JROT(6,7) JROT(6,8)
      JROT(7,8)
    }
    double ev = 0.0;
#pragma unroll
    for (int i2 = 0; i2 < 9; ++i2) if (jln == i2) ev = Bc[i2];
    if (jln < 9) {
      sEv[jln] = ev;
#pragma unroll
      for (int i2 = 0; i2 < 9; ++i2) sV[i2][jln] = Vc[i2];
    }
  }
  __syncthreads();

  if (tid == 0) {
    int jm = 0; double be = sEv[0];
#pragma unroll
    for (int jj = 1; jj < 9; ++jj) if (sEv[jj] < be) { be = sEv[jj]; jm = jj; }
    double F0[9];
#pragma unroll
    for (int i2 = 0; i2 < 9; ++i2) F0[i2] = sV[i2][jm];
    double M00 = F0[0], M01 = F0[1], M02 = F0[2];
    double M10 = F0[3], M11 = F0[4], M12 = F0[5];
    double M20 = F0[6], M21 = F0[7], M22 = F0[8];
    double A3[3][3], V3[3][3];
    A3[0][0] = M00*M00 + M10*M10 + M20*M20;
    A3[0][1] = M00*M01 + M10*M11 + M20*M21;
    A3[0][2] = M00*M02 + M10*M12 + M20*M22;
    A3[1][1] = M01*M01 + M11*M11 + M21*M21;
    A3[1][2] = M01*M02 + M11*M12 + M21*M22;
    A3[2][2] = M02*M02 + M12*M12 + M22*M22;
    A3[1][0] = A3[0][1]; A3[2][0] = A3[0][2]; A3[2][1] = A3[1][2];
#pragma unroll
    for (int ii = 0; ii < 3; ++ii)
#pragma unroll
      for (int jj = 0; jj < 3; ++jj) V3[ii][jj] = (ii == jj) ? 1.0 : 0.0;
    for (int sw = 0; sw < 10; ++sw) { ROT3(0,1) ROT3(0,2) ROT3(1,2) }
    double w0 = A3[0][0], w1 = A3[1][1], w2 = A3[2][2];
    double vx, vy, vz;
    if (w0 <= w1 && w0 <= w2)      { vx = V3[0][0]; vy = V3[1][0]; vz = V3[2][0]; }
    else if (w1 <= w2)             { vx = V3[0][1]; vy = V3[1][1]; vz = V3[2][1]; }
    else                           { vx = V3[0][2]; vy = V3[1][2]; vz = V3[2][2]; }
    double Mv0 = M00 * vx + M01 * vy + M02 * vz;
    double Mv1 = M10 * vx + M11 * vy + M12 * vz;
    double Mv2 = M20 * vx + M21 * vy + M22 * vz;
    double F200 = M00 - Mv0 * vx, F201 = M01 - Mv0 * vy, F202 = M02 - Mv0 * vz;
    double F210 = M10 - Mv1 * vx, F211 = M11 - Mv1 * vy, F212 = M12 - Mv1 * vz;
    double F220 = M20 - Mv2 * vx, F221 = M21 - Mv2 * vy, F222 = M22 - Mv2 * vz;
    double R00 = s2 * F200, R01 = s2 * F201, R02 = s2 * F202;
    double R10 = s2 * F210, R11 = s2 * F211, R12 = s2 * F212;
    double R20 = -s2 * m2x * F200 - s2 * m2y * F210 + F220;
    double R21 = -s2 * m2x * F201 - s2 * m2y * F211 + F221;
    double R22 = -s2 * m2x * F202 - s2 * m2y * F212 + F222;
    double D00 = s1 * R00, D10 = s1 * R10, D20 = s1 * R20;
    double D01 = s1 * R01, D11 = s1 * R11, D21 = s1 * R21;
    double D02 = -s1 * m1x * R00 - s1 * m1y * R01 + R02;
    double D12 = -s1 * m1x * R10 - s1 * m1y * R11 + R12;
    double D22 = -s1 * m1x * R20 - s1 * m1y * R21 + R22;
    Fout[0] = D00 / D22; Fout[1] = D01 / D22; Fout[2] = D02 / D22;
    Fout[3] = D10 / D22; Fout[4] = D11 / D22; Fout[5] = D12 / D22;
    Fout[6] = D20 / D22; Fout[7] = D21 / D22; Fout[8] = D22 / D22;
  }
}

// ---------------------------------------------------------------------------
// Kernel 3: cost matrix (unchanged)
// ---------------------------------------------------------------------------
__global__ __launch_bounds__(256) void cost_kernel(
    const float* __restrict__ feat1,
    const float* __restrict__ feat2,
    const float* __restrict__ pts1,
    const float* __restrict__ pts2,
    const double* __restrict__ Fd,
    float* __restrict__ Cout) {
  __shared__ float D1[128][68];
  __shared__ float D2[128][68];
  __shared__ float a0s[64], a1s[64], a2s[64], p2xs[64], p2ys[64];
  const int tid = threadIdx.x;
  const int rowbase = blockIdx.y * 64;
  const int colbase = blockIdx.x * 64;
#pragma unroll
  for (int it = 0; it < 32; ++it) {
    int idx = it * 256 + tid;
    int r = idx >> 7, k = idx & 127;
    D1[k][r] = feat1[(size_t)(rowbase + r) * FEAT + 2 + k];
    D2[k][r] = feat2[(size_t)(colbase + r) * FEAT + 2 + k];
  }
  if (tid < 64) {
    float x1 = pts1[2 * (rowbase + tid)], y1 = pts1[2 * (rowbase + tid) + 1];
    a0s[tid] = (float)(Fd[0] * x1 + Fd[3] * y1 + Fd[6]);
    a1s[tid] = (float)(Fd[1] * x1 + Fd[4] * y1 + Fd[7]);
    a2s[tid] = (float)(Fd[2] * x1 + Fd[5] * y1 + Fd[8]);
    p2xs[tid] = pts2[2 * (colbase + tid)];
    p2ys[tid] = pts2[2 * (colbase + tid) + 1];
  }
  __syncthreads();
  const int tx = tid & 15, ty = tid >> 4;
  float acc[4][4] = {};
#pragma unroll 4
  for (int k = 0; k < 128; ++k) {
    float4 av = *(const float4*)&D1[k][ty * 4];
    float4 bv = *(const float4*)&D2[k][tx * 4];
    float ar[4] = {av.x, av.y, av.z, av.w};
    float br[4] = {bv.x, bv.y, bv.z, bv.w};
#pragma unroll
    for (int r = 0; r < 4; ++r)
#pragma unroll
      for (int c = 0; c < 4; ++c)
        acc[r][c] += fabsf(ar[r] - br[c]);
  }
#pragma unroll
  for (int r = 0; r < 4; ++r) {
    int row = rowbase + ty * 4 + r;
    float a0 = a0s[ty * 4 + r], a1 = a1s[ty * 4 + r], a2 = a2s[ty * 4 + r];
    float4 o;
    float* op = &o.x;
#pragma unroll
    for (int c = 0; c < 4; ++c) {
      float kp = fabsf(a0 * p2xs[tx * 4 + c] + a1 * p2ys[tx * 4 + c] + a2);
      op[c] = acc[r][c] + kp;
    }
    *(float4*)&Cout[(size_t)row * BN + colbase + tx * 4] = o;
  }
}

// ---------------------------------------------------------------------------
// Kernel 4: LAP — double reduction (R5 math, bit-identical) + tight claims +
// SAP with an early-issue restructured pop loop: the winner lane is resolved
// (incl. exact tie fallback) BEFORE the next row's load is issued, and all
// minval/shp/rem/ui bookkeeping executes inside the load shadow.
// One wave per batch; state in registers (lane L owns cols/rows 4L..4L+3).
// ---------------------------------------------------------------------------
#define NROWS_C 152

__device__ __forceinline__ unsigned long long sortkey(double d) {
  long long b = __double_as_longlong(d);
  long long m = (b >> 63) | (long long)0x8000000000000000LL;
  return (unsigned long long)(b ^ m);
}
__device__ __forceinline__ double unsortkey(unsigned long long k) {
  unsigned long long m = ((long long)k < 0) ? 0x8000000000000000ULL
                                            : 0xFFFFFFFFFFFFFFFFULL;
  return __longlong_as_double((long long)(k ^ m));
}

// DPP min step: old = x so row_mask-disabled / invalid-source lanes are no-ops
template<int CTRL, int RM>
__device__ __forceinline__ unsigned dppm32(unsigned x) {
  int y = __builtin_amdgcn_update_dpp((int)x, (int)x, CTRL, RM, 0xF, false);
  unsigned u = (unsigned)y;
  return u < x ? u : x;
}
template<int CTRL, int RM>
__device__ __forceinline__ unsigned long long dppm64(unsigned long long x) {
  int lo = (int)(unsigned)x, hi = (int)(unsigned)(x >> 32);
  int lo2 = __builtin_amdgcn_update_dpp(lo, lo, CTRL, RM, 0xF, false);
  int hi2 = __builtin_amdgcn_update_dpp(hi, hi, CTRL, RM, 0xF, false);
  unsigned long long y =
      ((unsigned long long)(unsigned)hi2 << 32) | (unsigned)lo2;
  return y < x ? y : x;
}

// wave-uniform min of a u32 across 64 lanes: shr-scan + row bcasts
__device__ __forceinline__ unsigned wave_min_u32(unsigned x) {
  unsigned h = dppm32<0x111, 0xF>(x);   // row_shr:1
  h = dppm32<0x112, 0xF>(h);            // row_shr:2
  h = dppm32<0x114, 0xF>(h);            // row_shr:4
  h = dppm32<0x118, 0xF>(h);            // row_shr:8 -> lane15/31/47/63 row mins
  h = dppm32<0x142, 0xA>(h);            // row_bcast15 (rows 1,3)
  h = dppm32<0x143, 0xC>(h);            // row_bcast31 (rows 2,3) -> lane63 all
  return (unsigned)__builtin_amdgcn_readlane((int)h, 63);
}
__device__ __forceinline__ unsigned long long wave_min_u64(unsigned long long x) {
  unsigned long long h = dppm64<0x111, 0xF>(x);
  h = dppm64<0x112, 0xF>(h);
  h = dppm64<0x114, 0xF>(h);
  h = dppm64<0x118, 0xF>(h);
  h = dppm64<0x142, 0xA>(h);
  h = dppm64<0x143, 0xC>(h);
  unsigned lo = (unsigned)__builtin_amdgcn_readlane((int)(unsigned)h, 63);
  unsigned hi = (unsigned)__builtin_amdgcn_readlane((int)(unsigned)(h >> 32), 63);
  return ((unsigned long long)hi << 32) | lo;
}

__device__ __forceinline__ double rl64(double x, int l) {
  long long bb = __double_as_longlong(x);
  int lo = __builtin_amdgcn_readlane((int)(bb & 0xFFFFFFFFLL), l);
  int hi = __builtin_amdgcn_readlane((int)(bb >> 32), l);
  return __longlong_as_double(((long long)hi << 32) | (unsigned)lo);
}
__device__ __forceinline__ unsigned long long rdpair(unsigned ghi, unsigned glo, int l) {
  return ((unsigned long long)(unsigned)__builtin_amdgcn_readlane((int)ghi, l) << 32)
       | (unsigned)__builtin_amdgcn_readlane((int)glo, l);
}

// relax: d = (base + c) - v, base = minval - u[i] (wave-uniform). Strict <.
#define UPD(K, CK, KK, PP) {                                           \
  double d_ = (base + (double)(CK)) - v##K;                            \
  unsigned long long nk_ = sortkey(d_);                                \
  bool a_ = ((rem >> (K)) & 1u) && (nk_ < (KK));                       \
  (KK) = a_ ? nk_ : (KK);                                              \
  (PP) = a_ ? i : (PP); }

#define ROWLOAD(I) ((I) < NROWS_C ? *(const float4*)&rcache[(I)][lane * 4]   \
                                  : *(const float4*)(Cb + (size_t)(I) * BN + lane * 4))

#define R4C_OF(LI) ((LI) == 0 ? r4c0 : (LI) == 1 ? r4c1 : (LI) == 2 ? r4c2 : r4c3)
#define U4_OF(LI)  ((LI) == 0 ? u40  : (LI) == 1 ? u41  : (LI) == 2 ? u42  : u43)

__global__ __launch_bounds__(64) void hungarian_kernel(
    const float* __restrict__ C, float* __restrict__ out_matches) {
  const int b = blockIdx.x;
  const int lane = threadIdx.x;
  __shared__ float rcache[NROWS_C][NN];   // 155648 B
  __shared__ int c4r_lds[NN];             // 1024 B
  __shared__ double u_sd[NN];             // 2048 B (f64 row duals)
  __shared__ int flist[NN];               // 1024 B
  const float* Cb = C + (size_t)b * NN * BN + (size_t)b * NN;

  for (int t = lane; t < NROWS_C * (NN / 4); t += 64) {
    int r = t >> 6, q = t & 63;
    *(float4*)&rcache[r][q * 4] = *(const float4*)(Cb + (size_t)r * BN + q * 4);
  }
  for (int r = lane; r < NN; r += 64) c4r_lds[r] = -1;
  __syncthreads();

  // ---- u0[i] = min_j C[i][j] (exact f32; C >= 0 -> bits monotone) ---------
  for (int i = 0; i < NN; ++i) {
    float4 cr = ROWLOAD(i);
    float m01 = fminf(cr.x, cr.y), m23 = fminf(cr.z, cr.w);
    unsigned gm = wave_min_u32(__float_as_uint(fminf(m01, m23)));
    if (lane == 0) u_sd[i] = (double)__uint_as_float(gm);
  }
  __syncthreads();

  // ---- v[j] = min_i (C[i][j] - u0[i]) with argmin (R5 math) ---------------
  double v0, v1, v2, v3;
  int am0 = 0, am1 = 0, am2 = 0, am3 = 0;
  {
    double c0 = DBL_MAX, c1 = DBL_MAX, c2 = DBL_MAX, c3 = DBL_MAX;
    for (int i = 0; i < NN; ++i) {
      float4 cr = ROWLOAD(i);
      double uu = u_sd[i];
      double s0 = (double)cr.x - uu; if (s0 < c0) { c0 = s0; am0 = i; }
      double s1 = (double)cr.y - uu; if (s1 < c1) { c1 = s1; am1 = i; }
      double s2 = (double)cr.z - uu; if (s2 < c2) { c2 = s2; am2 = i; }
      double s3 = (double)cr.w - uu; if (s3 < c3) { c3 = s3; am3 = i; }
    }
    v0 = c0; v1 = c1; v2 = c2; v3 = c3;
  }

  // ---- claim tight argmin rows (any maximal tight matching is valid) ------
  int r4c0, r4c1, r4c2, r4c3;
  { int old = atomicCAS(&c4r_lds[am0], -1, lane * 4 + 0); r4c0 = (old == -1) ? am0 : -1; }
  { int old = atomicCAS(&c4r_lds[am1], -1, lane * 4 + 1); r4c1 = (old == -1) ? am1 : -1; }
  { int old = atomicCAS(&c4r_lds[am2], -1, lane * 4 + 2); r4c2 = (old == -1) ? am2 : -1; }
  { int old = atomicCAS(&c4r_lds[am3], -1, lane * 4 + 3); r4c3 = (old == -1) ? am3 : -1; }
  __syncthreads();
  int c4r0 = c4r_lds[lane * 4 + 0];
  int c4r1 = c4r_lds[lane * 4 + 1];
  int c4r2 = c4r_lds[lane * 4 + 2];
  int c4r3 = c4r_lds[lane * 4 + 3];
  double u40 = (r4c0 >= 0) ? u_sd[r4c0] : 0.0;   // u-mirror of row r4c_k
  double u41 = (r4c1 >= 0) ? u_sd[r4c1] : 0.0;
  double u42 = (r4c2 >= 0) ? u_sd[r4c2] : 0.0;
  double u43 = (r4c3 >= 0) ? u_sd[r4c3] : 0.0;

  // ---- free-row list (deterministic ballot-prefix build) ------------------
  int totfree = 0;
  for (int r0 = 0; r0 < NN; r0 += 64) {
    bool fr = (c4r_lds[r0 + lane] < 0);
    unsigned long long mask = __ballot(fr);
    int idx = totfree + __builtin_popcountll(mask & ((1ULL << lane) - 1ULL));
    if (fr) flist[idx] = r0 + lane;
    totfree += (int)__builtin_popcountll(mask);
  }
  __syncthreads();

  const unsigned long long KMAX = 0xFFFFFFFFFFFFFFFFULL;

  // ---- shortest augmenting path for each free row -------------------------
  for (int fi = 0; fi < totfree; ++fi) {
    const int cur = flist[fi];
    unsigned long long k0 = KMAX, k1 = KMAX, k2 = KMAX, k3 = KMAX;
    int p0 = -1, p1 = -1, p2 = -1, p3 = -1;
    double shp0 = 0, shp1 = 0, shp2 = 0, shp3 = 0;  // shortest at pop time
    unsigned rem = 0xFu;
    double minval = 0.0;
    const double ucur0 = u_sd[cur];
    double ui = ucur0;
    int i = cur;
    int sink = -1;
    float4 cr = ROWLOAD(cur);
    while (true) {
      double base = minval - ui;
      UPD(0, cr.x, k0, p0)
      UPD(1, cr.y, k1, p1)
      UPD(2, cr.z, k2, p2)
      UPD(3, cr.w, k3, p3)
      unsigned long long m01 = k0 < k1 ? k0 : k1;
      unsigned long long m23 = k2 < k3 ? k2 : k3;
      unsigned long long kl = m01 < m23 ? m01 : m23;
      int myli = (k0 == kl) ? 0 : (k1 == kl) ? 1 : (k2 == kl) ? 2 : 3;
      // ---- resolve winner lane FIRST (exact; rare-tie fallback) ----
      unsigned hi = (unsigned)(kl >> 32);
      unsigned mh = wave_min_u32(hi);
      unsigned long long bal = __ballot(hi == mh);
      int wl; unsigned long long g; bool fast;
      if (__builtin_popcountll(bal) == 1) {
        wl = (int)__builtin_ctzll(bal);
        fast = true; g = 0;
      } else {
        g = wave_min_u64(kl);
        bal = __ballot(kl == g);
        wl = (int)__builtin_ctzll(bal);
        fast = false;
      }
      int li = __builtin_amdgcn_readlane(myli, wl);
      int myrc = R4C_OF(li);
      int rc = __builtin_amdgcn_readlane(myrc, wl);
      // ---- issue next row load EARLY (wave-uniform rc) ----
      float4 nxt;
      if (rc >= 0) nxt = ROWLOAD(rc);
      // ---- bookkeeping in the load shadow ----
      if (fast) g = rdpair(hi, (unsigned)kl, wl);
      minval = unsortkey(g);
      double mu = U4_OF(li);
      if (lane == wl) {
        if (li == 0)      { k0 = KMAX; shp0 = minval; }
        else if (li == 1) { k1 = KMAX; shp1 = minval; }
        else if (li == 2) { k2 = KMAX; shp2 = minval; }
        else              { k3 = KMAX; shp3 = minval; }
        rem &= ~(1u << li);
      }
      if (rc < 0) { sink = wl * 4 + li; break; }
      ui = rl64(mu, wl);
      i = rc;
      cr = nxt;
    }
    // dual updates (scanned columns; sink included with exact-zero delta)
    if (!(rem & 1u)) { double dl = minval - shp0; v0 -= dl; if (r4c0 >= 0) u40 += dl; }
    if (!(rem & 2u)) { double dl = minval - shp1; v1 -= dl; if (r4c1 >= 0) u41 += dl; }
    if (!(rem & 4u)) { double dl = minval - shp2; v2 -= dl; if (r4c2 >= 0) u42 += dl; }
    if (!(rem & 8u)) { double dl = minval - shp3; v3 -= dl; if (r4c3 >= 0) u43 += dl; }
    // augment along the alternating path; maintain (r4c, u4c, c4r) mirrors
    int j = sink;
    while (true) {
      int slot = j & 3, ow = j >> 2;
      int myp = (slot == 0) ? p0 : (slot == 1) ? p1 : (slot == 2) ? p2 : p3;
      int i2 = __builtin_amdgcn_readlane(myp, ow);
      int s2 = i2 & 3, ow2 = i2 >> 2;
      int myc = (s2 == 0) ? c4r0 : (s2 == 1) ? c4r1 : (s2 == 2) ? c4r2 : c4r3;
      int jn = __builtin_amdgcn_readlane(myc, ow2);  // old col4row[i2] (-1 iff i2==cur)
      double newu;
      if (i2 == cur) {
        newu = ucur0 + minval;                       // u[cur] += minval
      } else {
        int slj = jn & 3, owj = jn >> 2;
        double myuj = (slj == 0) ? u40 : (slj == 1) ? u41
                    : (slj == 2) ? u42 : u43;
        newu = rl64(myuj, owj);                      // u[i2] post-dual-update
      }
      if (lane == ow) {
        if (slot == 0) { r4c0 = i2; u40 = newu; }
        else if (slot == 1) { r4c1 = i2; u41 = newu; }
        else if (slot == 2) { r4c2 = i2; u42 = newu; }
        else { r4c3 = i2; u43 = newu; }
      }
      if (lane == ow2) {
        if (s2 == 0) c4r0 = j; else if (s2 == 1) c4r1 = j;
        else if (s2 == 2) c4r2 = j; else c4r3 = j;
      }
      if (i2 == cur) break;
      j = jn;
    }
  }

  float4 ridx, cidx;
  ridx.x = (float)(lane * 4 + 0); ridx.y = (float)(lane * 4 + 1);
  ridx.z = (float)(lane * 4 + 2); ridx.w = (float)(lane * 4 + 3);
  cidx.x = (float)c4r0; cidx.y = (float)c4r1;
  cidx.z = (float)c4r2; cidx.w = (float)c4r3;
  *(float4*)&out_matches[b * 2 * NN + lane * 4] = ridx;
  *(float4*)&out_matches[b * 2 * NN + NN + lane * 4] = cidx;
}

// ---------------------------------------------------------------------------
extern "C" void kernel_launch(void* const* d_in, const int* in_sizes, int n_in,
                              void* d_out, int out_size, void* d_ws, size_t ws_size,
                              hipStream_t stream) {
  const float* theta = (const float*)d_in[0];
  const float* feat1 = (const float*)d_in[1];   // my_feature
  const float* feat2 = (const float*)d_in[2];   // my_tf_feature
  const int* wp = (const int*)d_in[3];
  const int* hp = (const int*)d_in[4];
  float* out = (float*)d_out;

  float* pts1 = (float*)d_ws;                  // 4096 floats
  float* pts2 = pts1 + 2 * BN;                 // 4096 floats
  double* Fd = (double*)(pts2 + 2 * BN);       // 9 doubles

  prep_kernel<<<BN / 256, 256, 0, stream>>>(theta, feat1, feat2, wp, hp, pts1, pts2);
  fmat_kernel<<<1, 256, 0, stream>>>(pts1, pts2, Fd);
  dim3 grid(BN / 64, BN / 64);
  cost_kernel<<<grid, 256, 0, stream>>>(feat1, feat2, pts1, pts2, Fd, out);
  hungarian_kernel<<<BB, 64, 0, stream>>>(out, out + (size_t)BN * BN);
}

// Round 9
// 1733.325 us; speedup vs baseline: 1.1909x; 1.1454x over previous
//
#include <hip/hip_runtime.h>
#include <hip/hip_bf16.h>
#include <cfloat>
#include <math.h>

// Problem constants
#define BB 8
#define NN 256
#define BN 2048           // B*N
#define DD 128            // descriptor dim
#define FEAT 130          // 2 + 128

// ---------------------------------------------------------------------------
// Kernel 1: point prep (unchanged)
// ---------------------------------------------------------------------------
__global__ __launch_bounds__(256) void prep_kernel(
    const float* __restrict__ theta,
    const float* __restrict__ feat1,   // my_feature   (BN,130)
    const float* __restrict__ feat2,   // my_tf_feature(BN,130)
    const int* __restrict__ wp, const int* __restrict__ hp,
    float* __restrict__ pts1, float* __restrict__ pts2) {
  int i = blockIdx.x * 256 + threadIdx.x;
  if (i >= BN) return;
  double W = (double)wp[0], H = (double)hp[0];
  double th = (double)theta[0];
  double c = cos(th), s = sin(th);
  double kx = (double)feat1[(size_t)i * FEAT + 0];
  double ky = (double)feat1[(size_t)i * FEAT + 1];
  double x = kx - 0.5 * W;
  double y = -ky + 0.5 * H;
  double calx = rint(c * x - s * y);   // jnp.round == round-half-even == rint
  double caly = rint(s * x + c * y);
  double ox = calx + 0.5 * W;
  double oy = -caly + 0.5 * H;
  pts2[2 * i]     = (float)(int)ox;    // astype(int32): trunc toward zero
  pts2[2 * i + 1] = (float)(int)oy;
  pts1[2 * i]     = (float)(int)feat2[(size_t)i * FEAT + 0];
  pts1[2 * i + 1] = (float)(int)feat2[(size_t)i * FEAT + 1];
}

// ---------------------------------------------------------------------------
// Kernel 2: fundamental 8-point (f64), unchanged (passing).
// ---------------------------------------------------------------------------
__device__ inline double wred(double x) {
#pragma unroll
  for (int off = 32; off > 0; off >>= 1) x += __shfl_down(x, off, 64);
  return x;
}

#define JROT(P, Q) {                                                          \
  double app_ = __shfl(Bc[P], P);                                             \
  double aqq_ = __shfl(Bc[Q], Q);                                             \
  double apq_ = __shfl(Bc[P], Q);                                             \
  double c_, s_;                                                              \
  if (fabs(apq_) > 1e-300) {                                                  \
    double tau_ = (aqq_ - app_) / (2.0 * apq_);                               \
    double t_ = (tau_ >= 0.0 ? 1.0 : -1.0) / (fabs(tau_) + sqrt(1.0 + tau_ * tau_)); \
    c_ = 1.0 / sqrt(1.0 + t_ * t_);                                           \
    s_ = t_ * c_;                                                             \
  } else { c_ = 1.0; s_ = 0.0; }                                              \
  const int prt_ = (jln == P) ? Q : ((jln == Q) ? P : jln);                   \
  const bool isP_ = (jln == P), isQ_ = (jln == Q);                            \
  _Pragma("unroll")                                                           \
  for (int ii = 0; ii < 9; ++ii) {                                            \
    double ob_ = __shfl(Bc[ii], prt_);                                        \
    double ov_ = __shfl(Vc[ii], prt_);                                        \
    if (isP_) { Bc[ii] = c_ * Bc[ii] - s_ * ob_; Vc[ii] = c_ * Vc[ii] - s_ * ov_; } \
    if (isQ_) { Bc[ii] = s_ * ob_ + c_ * Bc[ii]; Vc[ii] = s_ * ov_ + c_ * Vc[ii]; } \
  }                                                                           \
  { double rp_ = Bc[P], rq_ = Bc[Q];                                          \
    Bc[P] = c_ * rp_ - s_ * rq_; Bc[Q] = s_ * rp_ + c_ * rq_; } }

#define ROT3(P, Q) {                                                          \
  double apq_ = A3[P][Q];                                                     \
  double c_, s_;                                                              \
  if (fabs(apq_) > 1e-300) {                                                  \
    double tau_ = (A3[Q][Q] - A3[P][P]) / (2.0 * apq_);                       \
    double t_ = (tau_ >= 0.0 ? 1.0 : -1.0) / (fabs(tau_) + sqrt(1.0 + tau_ * tau_)); \
    c_ = 1.0 / sqrt(1.0 + t_ * t_); s_ = t_ * c_;                             \
  } else { c_ = 1.0; s_ = 0.0; }                                              \
  _Pragma("unroll")                                                           \
  for (int ii = 0; ii < 3; ++ii) { double a_ = A3[ii][P], b_ = A3[ii][Q];     \
    A3[ii][P] = c_ * a_ - s_ * b_; A3[ii][Q] = s_ * a_ + c_ * b_; }           \
  _Pragma("unroll")                                                           \
  for (int ii = 0; ii < 3; ++ii) { double a_ = A3[P][ii], b_ = A3[Q][ii];     \
    A3[P][ii] = c_ * a_ - s_ * b_; A3[Q][ii] = s_ * a_ + c_ * b_; }           \
  _Pragma("unroll")                                                           \
  for (int ii = 0; ii < 3; ++ii) { double a_ = V3[ii][P], b_ = V3[ii][Q];     \
    V3[ii][P] = c_ * a_ - s_ * b_; V3[ii][Q] = s_ * a_ + c_ * b_; } }

__global__ __launch_bounds__(256) void fmat_kernel(
    const float* __restrict__ pts1f, const float* __restrict__ pts2f,
    double* __restrict__ Fout) {
  __shared__ double sred[6];
  __shared__ double sATA[45];
  __shared__ double sV[9][16];
  __shared__ double sEv[16];
  const int tid = threadIdx.x;
  const int lane = tid & 63;
  if (tid < 6) sred[tid] = 0.0;
  if (tid < 45) sATA[tid] = 0.0;
  __syncthreads();

  double sx1 = 0, sy1 = 0, sx2 = 0, sy2 = 0;
  for (int p = tid; p < BN; p += 256) {
    sx1 += (double)pts1f[2 * p];     sy1 += (double)pts1f[2 * p + 1];
    sx2 += (double)pts2f[2 * p];     sy2 += (double)pts2f[2 * p + 1];
  }
  sx1 = wred(sx1); sy1 = wred(sy1); sx2 = wred(sx2); sy2 = wred(sy2);
  if (lane == 0) {
    atomicAdd(&sred[0], sx1); atomicAdd(&sred[1], sy1);
    atomicAdd(&sred[2], sx2); atomicAdd(&sred[3], sy2);
  }
  __syncthreads();
  const double m1x = sred[0] * (1.0 / BN), m1y = sred[1] * (1.0 / BN);
  const double m2x = sred[2] * (1.0 / BN), m2y = sred[3] * (1.0 / BN);

  double d1 = 0, d2 = 0;
  for (int p = tid; p < BN; p += 256) {
    double ax = (double)pts1f[2 * p] - m1x, ay = (double)pts1f[2 * p + 1] - m1y;
    double bx = (double)pts2f[2 * p] - m2x, by = (double)pts2f[2 * p + 1] - m2y;
    d1 += sqrt(ax * ax + ay * ay);
    d2 += sqrt(bx * bx + by * by);
  }
  d1 = wred(d1); d2 = wred(d2);
  if (lane == 0) { atomicAdd(&sred[4], d1); atomicAdd(&sred[5], d2); }
  __syncthreads();
  const double s1 = sqrt(2.0) / (sred[4] * (1.0 / BN));
  const double s2 = sqrt(2.0) / (sred[5] * (1.0 / BN));

  double acc45[45];
#pragma unroll
  for (int e = 0; e < 45; ++e) acc45[e] = 0.0;
  for (int p = tid; p < BN; p += 256) {
    double u1 = ((double)pts1f[2 * p]     - m1x) * s1;
    double v1 = ((double)pts1f[2 * p + 1] - m1y) * s1;
    double u2 = ((double)pts2f[2 * p]     - m2x) * s2;
    double v2 = ((double)pts2f[2 * p + 1] - m2y) * s2;
    double r[9] = {u2 * u1, u2 * v1, u2, v2 * u1, v2 * v1, v2, u1, v1, 1.0};
#pragma unroll
    for (int a = 0; a < 9; ++a)
#pragma unroll
      for (int b = a; b < 9; ++b)
        acc45[9 * a - (a * (a - 1)) / 2 + (b - a)] += r[a] * r[b];
  }
#pragma unroll
  for (int e = 0; e < 45; ++e) {
    double vv = wred(acc45[e]);
    if (lane == 0) atomicAdd(&sATA[e], vv);
  }
  __syncthreads();

  if (tid < 64) {
    const int jln = tid;
    double Bc[9], Vc[9];
#pragma unroll
    for (int i2 = 0; i2 < 9; ++i2) {
      if (jln < 9) {
        int a = i2 < jln ? i2 : jln;
        int b = i2 < jln ? jln : i2;
        Bc[i2] = sATA[9 * a - (a * (a - 1)) / 2 + (b - a)];
      } else Bc[i2] = 0.0;
      Vc[i2] = (i2 == jln) ? 1.0 : 0.0;
    }
    for (int sw = 0; sw < 7; ++sw) {
      JROT(0,1) JROT(0,2) JROT(0,3) JROT(0,4) JROT(0,5) JROT(0,6) JROT(0,7) JROT(0,8)
      JROT(1,2) JROT(1,3) JROT(1,4) JROT(1,5) JROT(1,6) JROT(1,7) JROT(1,8)
      JROT(2,3) JROT(2,4) JROT(2,5) JROT(2,6) JROT(2,7) JROT(2,8)
      JROT(3,4) JROT(3,5) JROT(3,6) JROT(3,7) JROT(3,8)
      JROT(4,5) JROT(4,6) JROT(4,7) JROT(4,8)
      JROT(5,6) JROT(5,7) JROT(5,8)
      JROT(6,7) JROT(6,8)
      JROT(7,8)
    }
    double ev = 0.0;
#pragma unroll
    for (int i2 = 0; i2 < 9; ++i2) if (jln == i2) ev = Bc[i2];
    if (jln < 9) {
      sEv[jln] = ev;
#pragma unroll
      for (int i2 = 0; i2 < 9; ++i2) sV[i2][jln] = Vc[i2];
    }
  }
  __syncthreads();

  if (tid == 0) {
    int jm = 0; double be = sEv[0];
#pragma unroll
    for (int jj = 1; jj < 9; ++jj) if (sEv[jj] < be) { be = sEv[jj]; jm = jj; }
    double F0[9];
#pragma unroll
    for (int i2 = 0; i2 < 9; ++i2) F0[i2] = sV[i2][jm];
    double M00 = F0[0], M01 = F0[1], M02 = F0[2];
    double M10 = F0[3], M11 = F0[4], M12 = F0[5];
    double M20 = F0[6], M21 = F0[7], M22 = F0[8];
    double A3[3][3], V3[3][3];
    A3[0][0] = M00*M00 + M10*M10 + M20*M20;
    A3[0][1] = M00*M01 + M10*M11 + M20*M21;
    A3[0][2] = M00*M02 + M10*M12 + M20*M22;
    A3[1][1] = M01*M01 + M11*M11 + M21*M21;
    A3[1][2] = M01*M02 + M11*M12 + M21*M22;
    A3[2][2] = M02*M02 + M12*M12 + M22*M22;
    A3[1][0] = A3[0][1]; A3[2][0] = A3[0][2]; A3[2][1] = A3[1][2];
#pragma unroll
    for (int ii = 0; ii < 3; ++ii)
#pragma unroll
      for (int jj = 0; jj < 3; ++jj) V3[ii][jj] = (ii == jj) ? 1.0 : 0.0;
    for (int sw = 0; sw < 10; ++sw) { ROT3(0,1) ROT3(0,2) ROT3(1,2) }
    double w0 = A3[0][0], w1 = A3[1][1], w2 = A3[2][2];
    double vx, vy, vz;
    if (w0 <= w1 && w0 <= w2)      { vx = V3[0][0]; vy = V3[1][0]; vz = V3[2][0]; }
    else if (w1 <= w2)             { vx = V3[0][1]; vy = V3[1][1]; vz = V3[2][1]; }
    else                           { vx = V3[0][2]; vy = V3[1][2]; vz = V3[2][2]; }
    double Mv0 = M00 * vx + M01 * vy + M02 * vz;
    double Mv1 = M10 * vx + M11 * vy + M12 * vz;
    double Mv2 = M20 * vx + M21 * vy + M22 * vz;
    double F200 = M00 - Mv0 * vx, F201 = M01 - Mv0 * vy, F202 = M02 - Mv0 * vz;
    double F210 = M10 - Mv1 * vx, F211 = M11 - Mv1 * vy, F212 = M12 - Mv1 * vz;
    double F220 = M20 - Mv2 * vx, F221 = M21 - Mv2 * vy, F222 = M22 - Mv2 * vz;
    double R00 = s2 * F200, R01 = s2 * F201, R02 = s2 * F202;
    double R10 = s2 * F210, R11 = s2 * F211, R12 = s2 * F212;
    double R20 = -s2 * m2x * F200 - s2 * m2y * F210 + F220;
    double R21 = -s2 * m2x * F201 - s2 * m2y * F211 + F221;
    double R22 = -s2 * m2x * F202 - s2 * m2y * F212 + F222;
    double D00 = s1 * R00, D10 = s1 * R10, D20 = s1 * R20;
    double D01 = s1 * R01, D11 = s1 * R11, D21 = s1 * R21;
    double D02 = -s1 * m1x * R00 - s1 * m1y * R01 + R02;
    double D12 = -s1 * m1x * R10 - s1 * m1y * R11 + R12;
    double D22 = -s1 * m1x * R20 - s1 * m1y * R21 + R22;
    Fout[0] = D00 / D22; Fout[1] = D01 / D22; Fout[2] = D02 / D22;
    Fout[3] = D10 / D22; Fout[4] = D11 / D22; Fout[5] = D12 / D22;
    Fout[6] = D20 / D22; Fout[7] = D21 / D22; Fout[8] = D22 / D22;
  }
}

// ---------------------------------------------------------------------------
// Kernel 3: cost matrix (unchanged)
// ---------------------------------------------------------------------------
__global__ __launch_bounds__(256) void cost_kernel(
    const float* __restrict__ feat1,
    const float* __restrict__ feat2,
    const float* __restrict__ pts1,
    const float* __restrict__ pts2,
    const double* __restrict__ Fd,
    float* __restrict__ Cout) {
  __shared__ float D1[128][68];
  __shared__ float D2[128][68];
  __shared__ float a0s[64], a1s[64], a2s[64], p2xs[64], p2ys[64];
  const int tid = threadIdx.x;
  const int rowbase = blockIdx.y * 64;
  const int colbase = blockIdx.x * 64;
#pragma unroll
  for (int it = 0; it < 32; ++it) {
    int idx = it * 256 + tid;
    int r = idx >> 7, k = idx & 127;
    D1[k][r] = feat1[(size_t)(rowbase + r) * FEAT + 2 + k];
    D2[k][r] = feat2[(size_t)(colbase + r) * FEAT + 2 + k];
  }
  if (tid < 64) {
    float x1 = pts1[2 * (rowbase + tid)], y1 = pts1[2 * (rowbase + tid) + 1];
    a0s[tid] = (float)(Fd[0] * x1 + Fd[3] * y1 + Fd[6]);
    a1s[tid] = (float)(Fd[1] * x1 + Fd[4] * y1 + Fd[7]);
    a2s[tid] = (float)(Fd[2] * x1 + Fd[5] * y1 + Fd[8]);
    p2xs[tid] = pts2[2 * (colbase + tid)];
    p2ys[tid] = pts2[2 * (colbase + tid) + 1];
  }
  __syncthreads();
  const int tx = tid & 15, ty = tid >> 4;
  float acc[4][4] = {};
#pragma unroll 4
  for (int k = 0; k < 128; ++k) {
    float4 av = *(const float4*)&D1[k][ty * 4];
    float4 bv = *(const float4*)&D2[k][tx * 4];
    float ar[4] = {av.x, av.y, av.z, av.w};
    float br[4] = {bv.x, bv.y, bv.z, bv.w};
#pragma unroll
    for (int r = 0; r < 4; ++r)
#pragma unroll
      for (int c = 0; c < 4; ++c)
        acc[r][c] += fabsf(ar[r] - br[c]);
  }
#pragma unroll
  for (int r = 0; r < 4; ++r) {
    int row = rowbase + ty * 4 + r;
    float a0 = a0s[ty * 4 + r], a1 = a1s[ty * 4 + r], a2 = a2s[ty * 4 + r];
    float4 o;
    float* op = &o.x;
#pragma unroll
    for (int c = 0; c < 4; ++c) {
      float kp = fabsf(a0 * p2xs[tx * 4 + c] + a1 * p2ys[tx * 4 + c] + a2);
      op[c] = acc[r][c] + kp;
    }
    *(float4*)&Cout[(size_t)row * BN + colbase + tx * 4] = o;
  }
}

// ---------------------------------------------------------------------------
// Kernel 4: LAP — double reduction + tight claims + SAP.
// Pop-loop chain restructured: own-slot values (sh, u-mirror, packed rc|li)
// precomputed per-lane BEFORE the reduce; after the winner lane is known,
// three INDEPENDENT readlanes fetch (li,rc), minval (= winner's f64 sh,
// bit-identical to unsortkey of the min key), and next-ui in parallel; the
// next row load issues immediately after. f64 sh slots replace the old shp
// (frozen at pop time by the rem guard). Math bit-identical to R5.
// ---------------------------------------------------------------------------
#define NROWS_C 152

__device__ __forceinline__ unsigned long long sortkey(double d) {
  long long b = __double_as_longlong(d);
  long long m = (b >> 63) | (long long)0x8000000000000000LL;
  return (unsigned long long)(b ^ m);
}

// DPP row_ror min (16-lane all-reduce after 4 stages: ror 1,2,4,8)
template<int CTRL>
__device__ __forceinline__ unsigned dpprm32(unsigned x) {
  int y = __builtin_amdgcn_update_dpp(0, (int)x, CTRL, 0xF, 0xF, true);
  unsigned u = (unsigned)y;
  return u < x ? u : x;
}
template<int CTRL>
__device__ __forceinline__ unsigned long long dpprm64(unsigned long long x) {
  int lo = (int)(unsigned)x, hi = (int)(unsigned)(x >> 32);
  int lo2 = __builtin_amdgcn_update_dpp(0, lo, CTRL, 0xF, 0xF, true);
  int hi2 = __builtin_amdgcn_update_dpp(0, hi, CTRL, 0xF, 0xF, true);
  unsigned long long y =
      ((unsigned long long)(unsigned)hi2 << 32) | (unsigned)lo2;
  return y < x ? y : x;
}

// wave-uniform min of u32 (4 ror stages + 4 parallel readlanes + scalar mins)
__device__ __forceinline__ unsigned wave_min_u32(unsigned x) {
  unsigned h = dpprm32<0x121>(x);
  h = dpprm32<0x122>(h);
  h = dpprm32<0x124>(h);
  h = dpprm32<0x128>(h);
  unsigned g0 = (unsigned)__builtin_amdgcn_readlane((int)h, 0);
  unsigned g1 = (unsigned)__builtin_amdgcn_readlane((int)h, 16);
  unsigned g2 = (unsigned)__builtin_amdgcn_readlane((int)h, 32);
  unsigned g3 = (unsigned)__builtin_amdgcn_readlane((int)h, 48);
  unsigned ga = g0 < g1 ? g0 : g1, gb = g2 < g3 ? g2 : g3;
  return ga < gb ? ga : gb;
}

__device__ __forceinline__ double rl64(double x, int l) {
  long long bb = __double_as_longlong(x);
  int lo = __builtin_amdgcn_readlane((int)(bb & 0xFFFFFFFFLL), l);
  int hi = __builtin_amdgcn_readlane((int)(bb >> 32), l);
  return __longlong_as_double(((long long)hi << 32) | (unsigned)lo);
}
__device__ __forceinline__ unsigned long long rdpair(unsigned ghi, unsigned glo, int l) {
  return ((unsigned long long)(unsigned)__builtin_amdgcn_readlane((int)ghi, l) << 32)
       | (unsigned)__builtin_amdgcn_readlane((int)glo, l);
}

// relax: d = (base + c) - v; strict < in f64 (== key order for finite values)
#define UPD(K, CK, KK, SH, PP) {                                       \
  double d_ = (base + (double)(CK)) - v##K;                            \
  bool a_ = ((rem >> (K)) & 1u) && (d_ < (SH));                        \
  (SH) = a_ ? d_ : (SH);                                               \
  (KK) = a_ ? sortkey(d_) : (KK);                                      \
  (PP) = a_ ? i : (PP); }

#define ROWLOAD(I) ((I) < NROWS_C ? *(const float4*)&rcache[(I)][lane * 4]   \
                                  : *(const float4*)(Cb + (size_t)(I) * BN + lane * 4))

#define R4C_OF(LI) ((LI) == 0 ? r4c0 : (LI) == 1 ? r4c1 : (LI) == 2 ? r4c2 : r4c3)
#define U4_OF(LI)  ((LI) == 0 ? u40  : (LI) == 1 ? u41  : (LI) == 2 ? u42  : u43)
#define SH_OF(LI)  ((LI) == 0 ? sh0  : (LI) == 1 ? sh1  : (LI) == 2 ? sh2  : sh3)

__global__ __launch_bounds__(64) void hungarian_kernel(
    const float* __restrict__ C, float* __restrict__ out_matches) {
  const int b = blockIdx.x;
  const int lane = threadIdx.x;
  __shared__ float rcache[NROWS_C][NN];   // 155648 B
  __shared__ int c4r_lds[NN];             // 1024 B
  __shared__ double u_sd[NN];             // 2048 B (f64 row duals)
  __shared__ int flist[NN];               // 1024 B
  const float* Cb = C + (size_t)b * NN * BN + (size_t)b * NN;

  for (int t = lane; t < NROWS_C * (NN / 4); t += 64) {
    int r = t >> 6, q = t & 63;
    *(float4*)&rcache[r][q * 4] = *(const float4*)(Cb + (size_t)r * BN + q * 4);
  }
  for (int r = lane; r < NN; r += 64) c4r_lds[r] = -1;
  __syncthreads();

  // ---- u0[i] = min_j C[i][j] (exact f32; C >= 0 -> bits monotone) ---------
  for (int i = 0; i < NN; ++i) {
    float4 cr = ROWLOAD(i);
    float m01 = fminf(cr.x, cr.y), m23 = fminf(cr.z, cr.w);
    unsigned gm = wave_min_u32(__float_as_uint(fminf(m01, m23)));
    if (lane == 0) u_sd[i] = (double)__uint_as_float(gm);
  }
  __syncthreads();

  // ---- v[j] = min_i (C[i][j] - u0[i]) with argmin -------------------------
  double v0, v1, v2, v3;
  int am0 = 0, am1 = 0, am2 = 0, am3 = 0;
  {
    double c0 = DBL_MAX, c1 = DBL_MAX, c2 = DBL_MAX, c3 = DBL_MAX;
    for (int i = 0; i < NN; ++i) {
      float4 cr = ROWLOAD(i);
      double uu = u_sd[i];
      double s0 = (double)cr.x - uu; if (s0 < c0) { c0 = s0; am0 = i; }
      double s1 = (double)cr.y - uu; if (s1 < c1) { c1 = s1; am1 = i; }
      double s2 = (double)cr.z - uu; if (s2 < c2) { c2 = s2; am2 = i; }
      double s3 = (double)cr.w - uu; if (s3 < c3) { c3 = s3; am3 = i; }
    }
    v0 = c0; v1 = c1; v2 = c2; v3 = c3;
  }

  // ---- claim tight argmin rows (any maximal tight matching is valid) ------
  int r4c0, r4c1, r4c2, r4c3;
  { int old = atomicCAS(&c4r_lds[am0], -1, lane * 4 + 0); r4c0 = (old == -1) ? am0 : -1; }
  { int old = atomicCAS(&c4r_lds[am1], -1, lane * 4 + 1); r4c1 = (old == -1) ? am1 : -1; }
  { int old = atomicCAS(&c4r_lds[am2], -1, lane * 4 + 2); r4c2 = (old == -1) ? am2 : -1; }
  { int old = atomicCAS(&c4r_lds[am3], -1, lane * 4 + 3); r4c3 = (old == -1) ? am3 : -1; }
  __syncthreads();
  int c4r0 = c4r_lds[lane * 4 + 0];
  int c4r1 = c4r_lds[lane * 4 + 1];
  int c4r2 = c4r_lds[lane * 4 + 2];
  int c4r3 = c4r_lds[lane * 4 + 3];
  double u40 = (r4c0 >= 0) ? u_sd[r4c0] : 0.0;   // u-mirror of row r4c_k
  double u41 = (r4c1 >= 0) ? u_sd[r4c1] : 0.0;
  double u42 = (r4c2 >= 0) ? u_sd[r4c2] : 0.0;
  double u43 = (r4c3 >= 0) ? u_sd[r4c3] : 0.0;

  // ---- free-row list (deterministic ballot-prefix build) ------------------
  int totfree = 0;
  for (int r0 = 0; r0 < NN; r0 += 64) {
    bool fr = (c4r_lds[r0 + lane] < 0);
    unsigned long long mask = __ballot(fr);
    int idx = totfree + __builtin_popcountll(mask & ((1ULL << lane) - 1ULL));
    if (fr) flist[idx] = r0 + lane;
    totfree += (int)__builtin_popcountll(mask);
  }
  __syncthreads();

  const unsigned long long KMAX = 0xFFFFFFFFFFFFFFFFULL;

  // ---- shortest augmenting path for each free row -------------------------
  for (int fi = 0; fi < totfree; ++fi) {
    const int cur = flist[fi];
    unsigned long long k0 = KMAX, k1 = KMAX, k2 = KMAX, k3 = KMAX;
    double sh0 = DBL_MAX, sh1 = DBL_MAX, sh2 = DBL_MAX, sh3 = DBL_MAX;
    int p0 = -1, p1 = -1, p2 = -1, p3 = -1;
    unsigned rem = 0xFu;
    double minval = 0.0;
    const double ucur0 = u_sd[cur];
    double ui = ucur0;
    int i = cur;
    int sink = -1;
    float4 cr = ROWLOAD(cur);
    while (true) {
      double base = minval - ui;
      UPD(0, cr.x, k0, sh0, p0)
      UPD(1, cr.y, k1, sh1, p1)
      UPD(2, cr.z, k2, sh2, p2)
      UPD(3, cr.w, k3, sh3, p3)
      unsigned long long m01 = k0 < k1 ? k0 : k1;
      unsigned long long m23 = k2 < k3 ? k2 : k3;
      unsigned long long kl = m01 < m23 ? m01 : m23;
      int myli = (k0 == kl) ? 0 : (k1 == kl) ? 1 : (k2 == kl) ? 2 : 3;
      // own-slot values, computed OFF the critical chain
      double mysh = SH_OF(myli);
      double myu  = U4_OF(myli);
      int myrc    = R4C_OF(myli);
      unsigned packed = ((unsigned)(myrc + 1) & 0xFFFFu) | ((unsigned)myli << 16);
      // hi-32 reduce (4 ror stages + 4 parallel readlanes)
      unsigned hi = (unsigned)(kl >> 32);
      unsigned mh = wave_min_u32(hi);
      unsigned long long bal = __ballot(hi == mh);
      int wl;
      if (__builtin_popcountll(bal) == 1) {
        wl = (int)__builtin_ctzll(bal);
      } else {                                   // exact u64 fallback (rare)
        unsigned long long gg = dpprm64<0x121>(kl);
        gg = dpprm64<0x122>(gg); gg = dpprm64<0x124>(gg); gg = dpprm64<0x128>(gg);
        unsigned glo2 = (unsigned)gg, ghi2 = (unsigned)(gg >> 32);
        unsigned long long r0 = rdpair(ghi2, glo2, 0);
        unsigned long long r1 = rdpair(ghi2, glo2, 16);
        unsigned long long r2 = rdpair(ghi2, glo2, 32);
        unsigned long long r3 = rdpair(ghi2, glo2, 48);
        unsigned long long ra = r0 < r1 ? r0 : r1, rb = r2 < r3 ? r2 : r3;
        unsigned long long g = ra < rb ? ra : rb;
        bal = __ballot(kl == g);
        wl = (int)__builtin_ctzll(bal);
      }
      // three INDEPENDENT broadcasts from the winner lane
      int pk = __builtin_amdgcn_readlane((int)packed, wl);
      minval = rl64(mysh, wl);                   // == winner's shortest, exact
      double uin = rl64(myu, wl);                // u of winner's matched row
      int rc = (pk & 0xFFFF) - 1;
      int li = pk >> 16;
      // issue next row load EARLY (wave-uniform rc)
      float4 nxt;
      if (rc >= 0) nxt = ROWLOAD(rc);
      // owner-lane state update (uses local myli; == li on lane wl)
      if (lane == wl) {
        if (myli == 0)      k0 = KMAX;
        else if (myli == 1) k1 = KMAX;
        else if (myli == 2) k2 = KMAX;
        else                k3 = KMAX;
        rem &= ~(1u << myli);
      }
      if (rc < 0) { sink = wl * 4 + li; break; }
      ui = uin;
      i = rc;
      cr = nxt;
    }
    // dual updates: sh holds pop-time shortest (frozen by rem guard);
    // sink included with exact-zero delta (its sh == final minval)
    if (!(rem & 1u)) { double dl = minval - sh0; v0 -= dl; if (r4c0 >= 0) u40 += dl; }
    if (!(rem & 2u)) { double dl = minval - sh1; v1 -= dl; if (r4c1 >= 0) u41 += dl; }
    if (!(rem & 4u)) { double dl = minval - sh2; v2 -= dl; if (r4c2 >= 0) u42 += dl; }
    if (!(rem & 8u)) { double dl = minval - sh3; v3 -= dl; if (r4c3 >= 0) u43 += dl; }
    // augment along the alternating path; maintain (r4c, u4c, c4r) mirrors
    int j = sink;
    while (true) {
      int slot = j & 3, ow = j >> 2;
      int myp = (slot == 0) ? p0 : (slot == 1) ? p1 : (slot == 2) ? p2 : p3;
      int i2 = __builtin_amdgcn_readlane(myp, ow);
      int s2 = i2 & 3, ow2 = i2 >> 2;
      int myc = (s2 == 0) ? c4r0 : (s2 == 1) ? c4r1 : (s2 == 2) ? c4r2 : c4r3;
      int jn = __builtin_amdgcn_readlane(myc, ow2);  // old col4row[i2] (-1 iff i2==cur)
      double newu;
      if (i2 == cur) {
        newu = ucur0 + minval;                       // u[cur] += minval
      } else {
        int slj = jn & 3, owj = jn >> 2;
        double myuj = (slj == 0) ? u40 : (slj == 1) ? u41
                    : (slj == 2) ? u42 : u43;
        newu = rl64(myuj, owj);                      // u[i2] post-dual-update
      }
      if (lane == ow) {
        if (slot == 0) { r4c0 = i2; u40 = newu; }
        else if (slot == 1) { r4c1 = i2; u41 = newu; }
        else if (slot == 2) { r4c2 = i2; u42 = newu; }
        else { r4c3 = i2; u43 = newu; }
      }
      if (lane == ow2) {
        if (s2 == 0) c4r0 = j; else if (s2 == 1) c4r1 = j;
        else if (s2 == 2) c4r2 = j; else c4r3 = j;
      }
      if (i2 == cur) break;
      j = jn;
    }
  }

  float4 ridx, cidx;
  ridx.x = (float)(lane * 4 + 0); ridx.y = (float)(lane * 4 + 1);
  ridx.z = (float)(lane * 4 + 2); ridx.w = (float)(lane * 4 + 3);
  cidx.x = (float)c4r0; cidx.y = (float)c4r1;
  cidx.z = (float)c4r2; cidx.w = (float)c4r3;
  *(float4*)&out_matches[b * 2 * NN + lane * 4] = ridx;
  *(float4*)&out_matches[b * 2 * NN + NN + lane * 4] = cidx;
}

// ---------------------------------------------------------------------------
extern "C" void kernel_launch(void* const* d_in, const int* in_sizes, int n_in,
                              void* d_out, int out_size, void* d_ws, size_t ws_size,
                              hipStream_t stream) {
  const float* theta = (const float*)d_in[0];
  const float* feat1 = (const float*)d_in[1];   // my_feature
  const float* feat2 = (const float*)d_in[2];   // my_tf_feature
  const int* wp = (const int*)d_in[3];
  const int* hp = (const int*)d_in[4];
  float* out = (float*)d_out;

  float* pts1 = (float*)d_ws;                  // 4096 floats
  float* pts2 = pts1 + 2 * BN;                 // 4096 floats
  double* Fd = (double*)(pts2 + 2 * BN);       // 9 doubles

  prep_kernel<<<BN / 256, 256, 0, stream>>>(theta, feat1, feat2, wp, hp, pts1, pts2);
  fmat_kernel<<<1, 256, 0, stream>>>(pts1, pts2, Fd);
  dim3 grid(BN / 64, BN / 64);
  cost_kernel<<<grid, 256, 0, stream>>>(feat1, feat2, pts1, pts2, Fd, out);
  hungarian_kernel<<<BB, 64, 0, stream>>>(out, out + (size_t)BN * BN);
}

// Round 10
// 1683.997 us; speedup vs baseline: 1.2258x; 1.0293x over previous
//
#include <hip/hip_runtime.h>
#include <hip/hip_bf16.h>
#include <cfloat>
#include <math.h>

// Problem constants
#define BB 8
#define NN 256
#define BN 2048           // B*N
#define DD 128            // descriptor dim
#define FEAT 130          // 2 + 128

// ---------------------------------------------------------------------------
// Kernel 1: fundamental 8-point (f64) with point-prep inlined (saves a
// launch). 5 Jacobi sweeps (converged by ~4; perturbation << f32 C noise).
// ---------------------------------------------------------------------------
__device__ inline double wred(double x) {
#pragma unroll
  for (int off = 32; off > 0; off >>= 1) x += __shfl_down(x, off, 64);
  return x;
}

#define JROT(P, Q) {                                                          \
  double app_ = __shfl(Bc[P], P);                                             \
  double aqq_ = __shfl(Bc[Q], Q);                                             \
  double apq_ = __shfl(Bc[P], Q);                                             \
  double c_, s_;                                                              \
  if (fabs(apq_) > 1e-300) {                                                  \
    double tau_ = (aqq_ - app_) / (2.0 * apq_);                               \
    double t_ = (tau_ >= 0.0 ? 1.0 : -1.0) / (fabs(tau_) + sqrt(1.0 + tau_ * tau_)); \
    c_ = 1.0 / sqrt(1.0 + t_ * t_);                                           \
    s_ = t_ * c_;                                                             \
  } else { c_ = 1.0; s_ = 0.0; }                                              \
  const int prt_ = (jln == P) ? Q : ((jln == Q) ? P : jln);                   \
  const bool isP_ = (jln == P), isQ_ = (jln == Q);                            \
  _Pragma("unroll")                                                           \
  for (int ii = 0; ii < 9; ++ii) {                                            \
    double ob_ = __shfl(Bc[ii], prt_);                                        \
    double ov_ = __shfl(Vc[ii], prt_);                                        \
    if (isP_) { Bc[ii] = c_ * Bc[ii] - s_ * ob_; Vc[ii] = c_ * Vc[ii] - s_ * ov_; } \
    if (isQ_) { Bc[ii] = s_ * ob_ + c_ * Bc[ii]; Vc[ii] = s_ * ov_ + c_ * Vc[ii]; } \
  }                                                                           \
  { double rp_ = Bc[P], rq_ = Bc[Q];                                          \
    Bc[P] = c_ * rp_ - s_ * rq_; Bc[Q] = s_ * rp_ + c_ * rq_; } }

#define ROT3(P, Q) {                                                          \
  double apq_ = A3[P][Q];                                                     \
  double c_, s_;                                                              \
  if (fabs(apq_) > 1e-300) {                                                  \
    double tau_ = (A3[Q][Q] - A3[P][P]) / (2.0 * apq_);                       \
    double t_ = (tau_ >= 0.0 ? 1.0 : -1.0) / (fabs(tau_) + sqrt(1.0 + tau_ * tau_)); \
    c_ = 1.0 / sqrt(1.0 + t_ * t_); s_ = t_ * c_;                             \
  } else { c_ = 1.0; s_ = 0.0; }                                              \
  _Pragma("unroll")                                                           \
  for (int ii = 0; ii < 3; ++ii) { double a_ = A3[ii][P], b_ = A3[ii][Q];     \
    A3[ii][P] = c_ * a_ - s_ * b_; A3[ii][Q] = s_ * a_ + c_ * b_; }           \
  _Pragma("unroll")                                                           \
  for (int ii = 0; ii < 3; ++ii) { double a_ = A3[P][ii], b_ = A3[Q][ii];     \
    A3[P][ii] = c_ * a_ - s_ * b_; A3[Q][ii] = s_ * a_ + c_ * b_; }           \
  _Pragma("unroll")                                                           \
  for (int ii = 0; ii < 3; ++ii) { double a_ = V3[ii][P], b_ = V3[ii][Q];     \
    V3[ii][P] = c_ * a_ - s_ * b_; V3[ii][Q] = s_ * a_ + c_ * b_; } }

__global__ __launch_bounds__(256) void fmat_kernel(
    const float* __restrict__ theta,
    const float* __restrict__ feat1,   // my_feature   (BN,130)
    const float* __restrict__ feat2,   // my_tf_feature(BN,130)
    const int* __restrict__ wp, const int* __restrict__ hp,
    float* pts1f, float* pts2f,
    double* __restrict__ Fout) {
  __shared__ double sred[6];
  __shared__ double sATA[45];
  __shared__ double sV[9][16];
  __shared__ double sEv[16];
  const int tid = threadIdx.x;
  const int lane = tid & 63;
  if (tid < 6) sred[tid] = 0.0;
  if (tid < 45) sATA[tid] = 0.0;

  // ---- inlined point prep (f64, matches np reference path) ----------------
  {
    double W = (double)wp[0], H = (double)hp[0];
    double th = (double)theta[0];
    double c = cos(th), s = sin(th);
    for (int i = tid; i < BN; i += 256) {
      double kx = (double)feat1[(size_t)i * FEAT + 0];
      double ky = (double)feat1[(size_t)i * FEAT + 1];
      double x = kx - 0.5 * W;
      double y = -ky + 0.5 * H;
      double calx = rint(c * x - s * y);   // jnp.round == rint (half-even)
      double caly = rint(s * x + c * y);
      double ox = calx + 0.5 * W;
      double oy = -caly + 0.5 * H;
      pts2f[2 * i]     = (float)(int)ox;   // astype(int32): trunc toward zero
      pts2f[2 * i + 1] = (float)(int)oy;
      pts1f[2 * i]     = (float)(int)feat2[(size_t)i * FEAT + 0];
      pts1f[2 * i + 1] = (float)(int)feat2[(size_t)i * FEAT + 1];
    }
  }
  __syncthreads();

  double sx1 = 0, sy1 = 0, sx2 = 0, sy2 = 0;
  for (int p = tid; p < BN; p += 256) {
    sx1 += (double)pts1f[2 * p];     sy1 += (double)pts1f[2 * p + 1];
    sx2 += (double)pts2f[2 * p];     sy2 += (double)pts2f[2 * p + 1];
  }
  sx1 = wred(sx1); sy1 = wred(sy1); sx2 = wred(sx2); sy2 = wred(sy2);
  if (lane == 0) {
    atomicAdd(&sred[0], sx1); atomicAdd(&sred[1], sy1);
    atomicAdd(&sred[2], sx2); atomicAdd(&sred[3], sy2);
  }
  __syncthreads();
  const double m1x = sred[0] * (1.0 / BN), m1y = sred[1] * (1.0 / BN);
  const double m2x = sred[2] * (1.0 / BN), m2y = sred[3] * (1.0 / BN);

  double d1 = 0, d2 = 0;
  for (int p = tid; p < BN; p += 256) {
    double ax = (double)pts1f[2 * p] - m1x, ay = (double)pts1f[2 * p + 1] - m1y;
    double bx = (double)pts2f[2 * p] - m2x, by = (double)pts2f[2 * p + 1] - m2y;
    d1 += sqrt(ax * ax + ay * ay);
    d2 += sqrt(bx * bx + by * by);
  }
  d1 = wred(d1); d2 = wred(d2);
  if (lane == 0) { atomicAdd(&sred[4], d1); atomicAdd(&sred[5], d2); }
  __syncthreads();
  const double s1 = sqrt(2.0) / (sred[4] * (1.0 / BN));
  const double s2 = sqrt(2.0) / (sred[5] * (1.0 / BN));

  double acc45[45];
#pragma unroll
  for (int e = 0; e < 45; ++e) acc45[e] = 0.0;
  for (int p = tid; p < BN; p += 256) {
    double u1 = ((double)pts1f[2 * p]     - m1x) * s1;
    double v1 = ((double)pts1f[2 * p + 1] - m1y) * s1;
    double u2 = ((double)pts2f[2 * p]     - m2x) * s2;
    double v2 = ((double)pts2f[2 * p + 1] - m2y) * s2;
    double r[9] = {u2 * u1, u2 * v1, u2, v2 * u1, v2 * v1, v2, u1, v1, 1.0};
#pragma unroll
    for (int a = 0; a < 9; ++a)
#pragma unroll
      for (int b = a; b < 9; ++b)
        acc45[9 * a - (a * (a - 1)) / 2 + (b - a)] += r[a] * r[b];
  }
#pragma unroll
  for (int e = 0; e < 45; ++e) {
    double vv = wred(acc45[e]);
    if (lane == 0) atomicAdd(&sATA[e], vv);
  }
  __syncthreads();

  if (tid < 64) {
    const int jln = tid;
    double Bc[9], Vc[9];
#pragma unroll
    for (int i2 = 0; i2 < 9; ++i2) {
      if (jln < 9) {
        int a = i2 < jln ? i2 : jln;
        int b = i2 < jln ? jln : i2;
        Bc[i2] = sATA[9 * a - (a * (a - 1)) / 2 + (b - a)];
      } else Bc[i2] = 0.0;
      Vc[i2] = (i2 == jln) ? 1.0 : 0.0;
    }
    for (int sw = 0; sw < 5; ++sw) {
      JROT(0,1) JROT(0,2) JROT(0,3) JROT(0,4) JROT(0,5) JROT(0,6) JROT(0,7) JROT(0,8)
      JROT(1,2) JROT(1,3) JROT(1,4) JROT(1,5) JROT(1,6) JROT(1,7) JROT(1,8)
      JROT(2,3) JROT(2,4) JROT(2,5) JROT(2,6) JROT(2,7) JROT(2,8)
      JROT(3,4) JROT(3,5) JROT(3,6) JROT(3,7) JROT(3,8)
      JROT(4,5) JROT(4,6) JROT(4,7) JROT(4,8)
      JROT(5,6) JROT(5,7) JROT(5,8)
      JROT(6,7) JROT(6,8)
      JROT(7,8)
    }
    double ev = 0.0;
#pragma unroll
    for (int i2 = 0; i2 < 9; ++i2) if (jln == i2) ev = Bc[i2];
    if (jln < 9) {
      sEv[jln] = ev;
#pragma unroll
      for (int i2 = 0; i2 < 9; ++i2) sV[i2][jln] = Vc[i2];
    }
  }
  __syncthreads();

  if (tid == 0) {
    int jm = 0; double be = sEv[0];
#pragma unroll
    for (int jj = 1; jj < 9; ++jj) if (sEv[jj] < be) { be = sEv[jj]; jm = jj; }
    double F0[9];
#pragma unroll
    for (int i2 = 0; i2 < 9; ++i2) F0[i2] = sV[i2][jm];
    double M00 = F0[0], M01 = F0[1], M02 = F0[2];
    double M10 = F0[3], M11 = F0[4], M12 = F0[5];
    double M20 = F0[6], M21 = F0[7], M22 = F0[8];
    double A3[3][3], V3[3][3];
    A3[0][0] = M00*M00 + M10*M10 + M20*M20;
    A3[0][1] = M00*M01 + M10*M11 + M20*M21;
    A3[0][2] = M00*M02 + M10*M12 + M20*M22;
    A3[1][1] = M01*M01 + M11*M11 + M21*M21;
    A3[1][2] = M01*M02 + M11*M12 + M21*M22;
    A3[2][2] = M02*M02 + M12*M12 + M22*M22;
    A3[1][0] = A3[0][1]; A3[2][0] = A3[0][2]; A3[2][1] = A3[1][2];
#pragma unroll
    for (int ii = 0; ii < 3; ++ii)
#pragma unroll
      for (int jj = 0; jj < 3; ++jj) V3[ii][jj] = (ii == jj) ? 1.0 : 0.0;
    for (int sw = 0; sw < 10; ++sw) { ROT3(0,1) ROT3(0,2) ROT3(1,2) }
    double w0 = A3[0][0], w1 = A3[1][1], w2 = A3[2][2];
    double vx, vy, vz;
    if (w0 <= w1 && w0 <= w2)      { vx = V3[0][0]; vy = V3[1][0]; vz = V3[2][0]; }
    else if (w1 <= w2)             { vx = V3[0][1]; vy = V3[1][1]; vz = V3[2][1]; }
    else                           { vx = V3[0][2]; vy = V3[1][2]; vz = V3[2][2]; }
    double Mv0 = M00 * vx + M01 * vy + M02 * vz;
    double Mv1 = M10 * vx + M11 * vy + M12 * vz;
    double Mv2 = M20 * vx + M21 * vy + M22 * vz;
    double F200 = M00 - Mv0 * vx, F201 = M01 - Mv0 * vy, F202 = M02 - Mv0 * vz;
    double F210 = M10 - Mv1 * vx, F211 = M11 - Mv1 * vy, F212 = M12 - Mv1 * vz;
    double F220 = M20 - Mv2 * vx, F221 = M21 - Mv2 * vy, F222 = M22 - Mv2 * vz;
    double R00 = s2 * F200, R01 = s2 * F201, R02 = s2 * F202;
    double R10 = s2 * F210, R11 = s2 * F211, R12 = s2 * F212;
    double R20 = -s2 * m2x * F200 - s2 * m2y * F210 + F220;
    double R21 = -s2 * m2x * F201 - s2 * m2y * F211 + F221;
    double R22 = -s2 * m2x * F202 - s2 * m2y * F212 + F222;
    double D00 = s1 * R00, D10 = s1 * R10, D20 = s1 * R20;
    double D01 = s1 * R01, D11 = s1 * R11, D21 = s1 * R21;
    double D02 = -s1 * m1x * R00 - s1 * m1y * R01 + R02;
    double D12 = -s1 * m1x * R10 - s1 * m1y * R11 + R12;
    double D22 = -s1 * m1x * R20 - s1 * m1y * R21 + R22;
    Fout[0] = D00 / D22; Fout[1] = D01 / D22; Fout[2] = D02 / D22;
    Fout[3] = D10 / D22; Fout[4] = D11 / D22; Fout[5] = D12 / D22;
    Fout[6] = D20 / D22; Fout[7] = D21 / D22; Fout[8] = D22 / D22;
  }
}

// ---------------------------------------------------------------------------
// Kernel 2: cost matrix (unchanged)
// ---------------------------------------------------------------------------
__global__ __launch_bounds__(256) void cost_kernel(
    const float* __restrict__ feat1,
    const float* __restrict__ feat2,
    const float* __restrict__ pts1,
    const float* __restrict__ pts2,
    const double* __restrict__ Fd,
    float* __restrict__ Cout) {
  __shared__ float D1[128][68];
  __shared__ float D2[128][68];
  __shared__ float a0s[64], a1s[64], a2s[64], p2xs[64], p2ys[64];
  const int tid = threadIdx.x;
  const int rowbase = blockIdx.y * 64;
  const int colbase = blockIdx.x * 64;
#pragma unroll
  for (int it = 0; it < 32; ++it) {
    int idx = it * 256 + tid;
    int r = idx >> 7, k = idx & 127;
    D1[k][r] = feat1[(size_t)(rowbase + r) * FEAT + 2 + k];
    D2[k][r] = feat2[(size_t)(colbase + r) * FEAT + 2 + k];
  }
  if (tid < 64) {
    float x1 = pts1[2 * (rowbase + tid)], y1 = pts1[2 * (rowbase + tid) + 1];
    a0s[tid] = (float)(Fd[0] * x1 + Fd[3] * y1 + Fd[6]);
    a1s[tid] = (float)(Fd[1] * x1 + Fd[4] * y1 + Fd[7]);
    a2s[tid] = (float)(Fd[2] * x1 + Fd[5] * y1 + Fd[8]);
    p2xs[tid] = pts2[2 * (colbase + tid)];
    p2ys[tid] = pts2[2 * (colbase + tid) + 1];
  }
  __syncthreads();
  const int tx = tid & 15, ty = tid >> 4;
  float acc[4][4] = {};
#pragma unroll 4
  for (int k = 0; k < 128; ++k) {
    float4 av = *(const float4*)&D1[k][ty * 4];
    float4 bv = *(const float4*)&D2[k][tx * 4];
    float ar[4] = {av.x, av.y, av.z, av.w};
    float br[4] = {bv.x, bv.y, bv.z, bv.w};
#pragma unroll
    for (int r = 0; r < 4; ++r)
#pragma unroll
      for (int c = 0; c < 4; ++c)
        acc[r][c] += fabsf(ar[r] - br[c]);
  }
#pragma unroll
  for (int r = 0; r < 4; ++r) {
    int row = rowbase + ty * 4 + r;
    float a0 = a0s[ty * 4 + r], a1 = a1s[ty * 4 + r], a2 = a2s[ty * 4 + r];
    float4 o;
    float* op = &o.x;
#pragma unroll
    for (int c = 0; c < 4; ++c) {
      float kp = fabsf(a0 * p2xs[tx * 4 + c] + a1 * p2ys[tx * 4 + c] + a2);
      op[c] = acc[r][c] + kp;
    }
    *(float4*)&Cout[(size_t)row * BN + colbase + tx * 4] = o;
  }
}

// ---------------------------------------------------------------------------
// Kernel 3: LAP — double reduction + tight claims + SAP.
// R10: keys merged into distances. All Dijkstra distances are provably >= 0
// (zero-slack case reduces exactly to v's defining expression), so raw IEEE
// f64 bits are monotone and the separate u64 sortkeys are redundant: lane-min
// runs on bits(sh) masked by rem (popped slots -> +inf). Ordering, tie-breaks
// (first-slot, lowest-lane, exact u64 fallback on hi-32 ties) identical.
// ---------------------------------------------------------------------------
#define NROWS_C 153

// DPP row_ror min (16-lane all-reduce after 4 stages: ror 1,2,4,8)
template<int CTRL>
__device__ __forceinline__ unsigned dpprm32(unsigned x) {
  int y = __builtin_amdgcn_update_dpp(0, (int)x, CTRL, 0xF, 0xF, true);
  unsigned u = (unsigned)y;
  return u < x ? u : x;
}
template<int CTRL>
__device__ __forceinline__ unsigned long long dpprm64(unsigned long long x) {
  int lo = (int)(unsigned)x, hi = (int)(unsigned)(x >> 32);
  int lo2 = __builtin_amdgcn_update_dpp(0, lo, CTRL, 0xF, 0xF, true);
  int hi2 = __builtin_amdgcn_update_dpp(0, hi, CTRL, 0xF, 0xF, true);
  unsigned long long y =
      ((unsigned long long)(unsigned)hi2 << 32) | (unsigned)lo2;
  return y < x ? y : x;
}

// wave-uniform min of u32 (4 ror stages + 4 parallel readlanes + scalar mins)
__device__ __forceinline__ unsigned wave_min_u32(unsigned x) {
  unsigned h = dpprm32<0x121>(x);
  h = dpprm32<0x122>(h);
  h = dpprm32<0x124>(h);
  h = dpprm32<0x128>(h);
  unsigned g0 = (unsigned)__builtin_amdgcn_readlane((int)h, 0);
  unsigned g1 = (unsigned)__builtin_amdgcn_readlane((int)h, 16);
  unsigned g2 = (unsigned)__builtin_amdgcn_readlane((int)h, 32);
  unsigned g3 = (unsigned)__builtin_amdgcn_readlane((int)h, 48);
  unsigned ga = g0 < g1 ? g0 : g1, gb = g2 < g3 ? g2 : g3;
  return ga < gb ? ga : gb;
}

__device__ __forceinline__ double rl64(double x, int l) {
  long long bb = __double_as_longlong(x);
  int lo = __builtin_amdgcn_readlane((int)(bb & 0xFFFFFFFFLL), l);
  int hi = __builtin_amdgcn_readlane((int)(bb >> 32), l);
  return __longlong_as_double(((long long)hi << 32) | (unsigned)lo);
}
__device__ __forceinline__ unsigned long long rdpair(unsigned ghi, unsigned glo, int l) {
  return ((unsigned long long)(unsigned)__builtin_amdgcn_readlane((int)ghi, l) << 32)
       | (unsigned)__builtin_amdgcn_readlane((int)glo, l);
}

// relax: d = (base + c) - v; strict < in f64. d >= 0 always (see header).
#define UPD(K, CK, SH, PP) {                                           \
  double d_ = (base + (double)(CK)) - v##K;                            \
  bool a_ = ((rem >> (K)) & 1u) && (d_ < (SH));                        \
  (SH) = a_ ? d_ : (SH);                                               \
  (PP) = a_ ? i : (PP); }

#define ROWLOAD(I) ((I) < NROWS_C ? *(const float4*)&rcache[(I)][lane * 4]   \
                                  : *(const float4*)(Cb + (size_t)(I) * BN + lane * 4))

#define R4C_OF(LI) ((LI) == 0 ? r4c0 : (LI) == 1 ? r4c1 : (LI) == 2 ? r4c2 : r4c3)
#define U4_OF(LI)  ((LI) == 0 ? u40  : (LI) == 1 ? u41  : (LI) == 2 ? u42  : u43)
#define SH_OF(LI)  ((LI) == 0 ? sh0  : (LI) == 1 ? sh1  : (LI) == 2 ? sh2  : sh3)

__global__ __launch_bounds__(64) void hungarian_kernel(
    const float* __restrict__ C, float* __restrict__ out_matches) {
  const int b = blockIdx.x;
  const int lane = threadIdx.x;
  __shared__ float rcache[NROWS_C][NN];   // 156672 B
  __shared__ int c4r_lds[NN];             // 1024 B (claims; later aliased as flist)
  __shared__ double u_sd[NN];             // 2048 B (f64 row duals)
  const float* Cb = C + (size_t)b * NN * BN + (size_t)b * NN;

  for (int t = lane; t < NROWS_C * (NN / 4); t += 64) {
    int r = t >> 6, q = t & 63;
    *(float4*)&rcache[r][q * 4] = *(const float4*)(Cb + (size_t)r * BN + q * 4);
  }
  for (int r = lane; r < NN; r += 64) c4r_lds[r] = -1;
  __syncthreads();

  // ---- u0[i] = min_j C[i][j] (exact f32; C >= 0 -> bits monotone) ---------
  for (int i = 0; i < NN; ++i) {
    float4 cr = ROWLOAD(i);
    float m01 = fminf(cr.x, cr.y), m23 = fminf(cr.z, cr.w);
    unsigned gm = wave_min_u32(__float_as_uint(fminf(m01, m23)));
    if (lane == 0) u_sd[i] = (double)__uint_as_float(gm);
  }
  __syncthreads();

  // ---- v[j] = min_i (C[i][j] - u0[i]) with argmin -------------------------
  double v0, v1, v2, v3;
  int am0 = 0, am1 = 0, am2 = 0, am3 = 0;
  {
    double c0 = DBL_MAX, c1 = DBL_MAX, c2 = DBL_MAX, c3 = DBL_MAX;
    for (int i = 0; i < NN; ++i) {
      float4 cr = ROWLOAD(i);
      double uu = u_sd[i];
      double s0 = (double)cr.x - uu; if (s0 < c0) { c0 = s0; am0 = i; }
      double s1 = (double)cr.y - uu; if (s1 < c1) { c1 = s1; am1 = i; }
      double s2 = (double)cr.z - uu; if (s2 < c2) { c2 = s2; am2 = i; }
      double s3 = (double)cr.w - uu; if (s3 < c3) { c3 = s3; am3 = i; }
    }
    v0 = c0; v1 = c1; v2 = c2; v3 = c3;
  }

  // ---- claim tight argmin rows (any maximal tight matching is valid) ------
  int r4c0, r4c1, r4c2, r4c3;
  { int old = atomicCAS(&c4r_lds[am0], -1, lane * 4 + 0); r4c0 = (old == -1) ? am0 : -1; }
  { int old = atomicCAS(&c4r_lds[am1], -1, lane * 4 + 1); r4c1 = (old == -1) ? am1 : -1; }
  { int old = atomicCAS(&c4r_lds[am2], -1, lane * 4 + 2); r4c2 = (old == -1) ? am2 : -1; }
  { int old = atomicCAS(&c4r_lds[am3], -1, lane * 4 + 3); r4c3 = (old == -1) ? am3 : -1; }
  __syncthreads();
  int c4r0 = c4r_lds[lane * 4 + 0];
  int c4r1 = c4r_lds[lane * 4 + 1];
  int c4r2 = c4r_lds[lane * 4 + 2];
  int c4r3 = c4r_lds[lane * 4 + 3];
  double u40 = (r4c0 >= 0) ? u_sd[r4c0] : 0.0;   // u-mirror of row r4c_k
  double u41 = (r4c1 >= 0) ? u_sd[r4c1] : 0.0;
  double u42 = (r4c2 >= 0) ? u_sd[r4c2] : 0.0;
  double u43 = (r4c3 >= 0) ? u_sd[r4c3] : 0.0;

  // ---- free-row list (aliased onto c4r_lds; single-wave read-then-write ---
  //      per iteration, writes only land at indices <= rows already scanned)
  int* flist = c4r_lds;
  int totfree = 0;
  for (int r0 = 0; r0 < NN; r0 += 64) {
    bool fr = (c4r_lds[r0 + lane] < 0);
    unsigned long long mask = __ballot(fr);
    int idx = totfree + __builtin_popcountll(mask & ((1ULL << lane) - 1ULL));
    if (fr) flist[idx] = r0 + lane;
    totfree += (int)__builtin_popcountll(mask);
  }
  __syncthreads();

  const unsigned long long INF64 = 0x7FF0000000000000ULL;  // +inf bits

  // ---- shortest augmenting path for each free row -------------------------
  for (int fi = 0; fi < totfree; ++fi) {
    const int cur = flist[fi];
    double sh0 = DBL_MAX, sh1 = DBL_MAX, sh2 = DBL_MAX, sh3 = DBL_MAX;
    int p0 = -1, p1 = -1, p2 = -1, p3 = -1;
    unsigned rem = 0xFu;
    double minval = 0.0;
    const double ucur0 = u_sd[cur];
    double ui = ucur0;
    int i = cur;
    int sink = -1;
    float4 cr = ROWLOAD(cur);
    while (true) {
      double base = minval - ui;
      UPD(0, cr.x, sh0, p0)
      UPD(1, cr.y, sh1, p1)
      UPD(2, cr.z, sh2, p2)
      UPD(3, cr.w, sh3, p3)
      // lane-local min over remaining slots: raw f64 bits (monotone, d >= 0)
      unsigned long long b0 = (rem & 1u) ? (unsigned long long)__double_as_longlong(sh0) : INF64;
      unsigned long long b1 = (rem & 2u) ? (unsigned long long)__double_as_longlong(sh1) : INF64;
      unsigned long long b2 = (rem & 4u) ? (unsigned long long)__double_as_longlong(sh2) : INF64;
      unsigned long long b3 = (rem & 8u) ? (unsigned long long)__double_as_longlong(sh3) : INF64;
      unsigned long long m01 = b0 < b1 ? b0 : b1;
      unsigned long long m23 = b2 < b3 ? b2 : b3;
      unsigned long long kl = m01 < m23 ? m01 : m23;
      int myli = (b0 == kl) ? 0 : (b1 == kl) ? 1 : (b2 == kl) ? 2 : 3;
      // own-slot values, computed OFF the critical chain
      double mysh = SH_OF(myli);
      double myu  = U4_OF(myli);
      int myrc    = R4C_OF(myli);
      unsigned packed = ((unsigned)(myrc + 1) & 0xFFFFu) | ((unsigned)myli << 16);
      // hi-32 reduce (4 ror stages + 4 parallel readlanes)
      unsigned hi = (unsigned)(kl >> 32);
      unsigned mh = wave_min_u32(hi);
      unsigned long long bal = __ballot(hi == mh);
      int wl;
      if (__builtin_popcountll(bal) == 1) {
        wl = (int)__builtin_ctzll(bal);
      } else {                                   // exact u64 fallback (rare)
        unsigned long long gg = dpprm64<0x121>(kl);
        gg = dpprm64<0x122>(gg); gg = dpprm64<0x124>(gg); gg = dpprm64<0x128>(gg);
        unsigned glo2 = (unsigned)gg, ghi2 = (unsigned)(gg >> 32);
        unsigned long long r0 = rdpair(ghi2, glo2, 0);
        unsigned long long r1 = rdpair(ghi2, glo2, 16);
        unsigned long long r2 = rdpair(ghi2, glo2, 32);
        unsigned long long r3 = rdpair(ghi2, glo2, 48);
        unsigned long long ra = r0 < r1 ? r0 : r1, rb = r2 < r3 ? r2 : r3;
        unsigned long long g = ra < rb ? ra : rb;
        bal = __ballot(kl == g);
        wl = (int)__builtin_ctzll(bal);
      }
      // three INDEPENDENT broadcasts from the winner lane
      int pk = __builtin_amdgcn_readlane((int)packed, wl);
      minval = rl64(mysh, wl);                   // == winner's shortest, exact
      double uin = rl64(myu, wl);                // u of winner's matched row
      int rc = (pk & 0xFFFF) - 1;
      int li = pk >> 16;
      // issue next row load EARLY (wave-uniform rc)
      float4 nxt;
      if (rc >= 0) nxt = ROWLOAD(rc);
      // owner-lane state update (sh stays frozen; rem bit excludes the slot)
      if (lane == wl) rem &= ~(1u << myli);
      if (rc < 0) { sink = wl * 4 + li; break; }
      ui = uin;
      i = rc;
      cr = nxt;
    }
    // dual updates: sh holds pop-time shortest (frozen by rem guard);
    // sink included with exact-zero delta (its sh == final minval)
    if (!(rem & 1u)) { double dl = minval - sh0; v0 -= dl; if (r4c0 >= 0) u40 += dl; }
    if (!(rem & 2u)) { double dl = minval - sh1; v1 -= dl; if (r4c1 >= 0) u41 += dl; }
    if (!(rem & 4u)) { double dl = minval - sh2; v2 -= dl; if (r4c2 >= 0) u42 += dl; }
    if (!(rem & 8u)) { double dl = minval - sh3; v3 -= dl; if (r4c3 >= 0) u43 += dl; }
    // augment along the alternating path; maintain (r4c, u4c, c4r) mirrors
    int j = sink;
    while (true) {
      int slot = j & 3, ow = j >> 2;
      int myp = (slot == 0) ? p0 : (slot == 1) ? p1 : (slot == 2) ? p2 : p3;
      int i2 = __builtin_amdgcn_readlane(myp, ow);
      int s2 = i2 & 3, ow2 = i2 >> 2;
      int myc = (s2 == 0) ? c4r0 : (s2 == 1) ? c4r1 : (s2 == 2) ? c4r2 : c4r3;
      int jn = __builtin_amdgcn_readlane(myc, ow2);  // old col4row[i2] (-1 iff i2==cur)
      double newu;
      if (i2 == cur) {
        newu = ucur0 + minval;                       // u[cur] += minval
      } else {
        int slj = jn & 3, owj = jn >> 2;
        double myuj = (slj == 0) ? u40 : (slj == 1) ? u41
                    : (slj == 2) ? u42 : u43;
        newu = rl64(myuj, owj);                      // u[i2] post-dual-update
      }
      if (lane == ow) {
        if (slot == 0) { r4c0 = i2; u40 = newu; }
        else if (slot == 1) { r4c1 = i2; u41 = newu; }
        else if (slot == 2) { r4c2 = i2; u42 = newu; }
        else { r4c3 = i2; u43 = newu; }
      }
      if (lane == ow2) {
        if (s2 == 0) c4r0 = j; else if (s2 == 1) c4r1 = j;
        else if (s2 == 2) c4r2 = j; else c4r3 = j;
      }
      if (i2 == cur) break;
      j = jn;
    }
  }

  float4 ridx, cidx;
  ridx.x = (float)(lane * 4 + 0); ridx.y = (float)(lane * 4 + 1);
  ridx.z = (float)(lane * 4 + 2); ridx.w = (float)(lane * 4 + 3);
  cidx.x = (float)c4r0; cidx.y = (float)c4r1;
  cidx.z = (float)c4r2; cidx.w = (float)c4r3;
  *(float4*)&out_matches[b * 2 * NN + lane * 4] = ridx;
  *(float4*)&out_matches[b * 2 * NN + NN + lane * 4] = cidx;
}

// ---------------------------------------------------------------------------
extern "C" void kernel_launch(void* const* d_in, const int* in_sizes, int n_in,
                              void* d_out, int out_size, void* d_ws, size_t ws_size,
                              hipStream_t stream) {
  const float* theta = (const float*)d_in[0];
  const float* feat1 = (const float*)d_in[1];   // my_feature
  const float* feat2 = (const float*)d_in[2];   // my_tf_feature
  const int* wp = (const int*)d_in[3];
  const int* hp = (const int*)d_in[4];
  float* out = (float*)d_out;

  float* pts1 = (float*)d_ws;                  // 4096 floats
  float* pts2 = pts1 + 2 * BN;                 // 4096 floats
  double* Fd = (double*)(pts2 + 2 * BN);       // 9 doubles

  fmat_kernel<<<1, 256, 0, stream>>>(theta, feat1, feat2, wp, hp, pts1, pts2, Fd);
  dim3 grid(BN / 64, BN / 64);
  cost_kernel<<<grid, 256, 0, stream>>>(feat1, feat2, pts1, pts2, Fd, out);
  hungarian_kernel<<<BB, 64, 0, stream>>>(out, out + (size_t)BN * BN);
}